// Round 12
// baseline (66.726 us; speedup 1.0000x reference)
//
#include <hip/hip_runtime.h>
#include <hip/hip_bf16.h>

// Problem dims
#define BB 4
#define SS 1024
#define EE 192
#define HH 64
// D = 3 (head dim)

constexpr int BH = BB * HH;  // 256

typedef __attribute__((ext_vector_type(8))) short bs8;    // 8 bf16 = 4 VGPR (MFMA A/B frag)
typedef __attribute__((ext_vector_type(16))) float fx16;  // MFMA C/D frag
union U4B { uint4 u; bs8 s; };

// ws layout (float units)
constexpr size_t OFF_QF  = 0;                             // (B*H,S,4) bf16: q0 q1 q2 0
constexpr size_t OFF_KF  = OFF_QF  + (size_t)BH*SS*2;     // (B*H,S,4) bf16: k0 k1 k2 0
constexpr size_t OFF_VC  = OFF_KF  + (size_t)BH*SS*2;     // (B*H,3,S) bf16 col-major
constexpr size_t OFF_AOH = OFF_VC  + (size_t)BH*SS*3/2;   // (B,S,E) bf16 hi
constexpr size_t OFF_AOL = OFF_AOH + (size_t)BB*SS*EE/2;  // (B,S,E) bf16 lo
constexpr size_t OFF_WCH = OFF_AOL + (size_t)BB*SS*EE/2;  // (576,192) bf16 hi (WqR|WkR|Wv)
constexpr size_t OFF_WCL = OFF_WCH + (size_t)576*EE/2;    // lo
constexpr size_t OFF_WOH = OFF_WCL + (size_t)576*EE/2;    // (192,192) bf16 hi (Wo)
constexpr size_t OFF_WOL = OFF_WOH + (size_t)EE*EE/2;     // lo

static __device__ __forceinline__ float fast_exp2(float x) {
#if __has_builtin(__builtin_amdgcn_exp2f)
  return __builtin_amdgcn_exp2f(x);
#else
  return exp2f(x);
#endif
}
static __device__ __forceinline__ float fast_rcp(float x) {
#if __has_builtin(__builtin_amdgcn_rcpf)
  return __builtin_amdgcn_rcpf(x);
#else
  return 1.0f / x;
#endif
}

// split a pair of fp32 into packed bf16 hi + bf16 lo (lo = residual)
static __device__ __forceinline__ void split2(float a, float b, unsigned& hi, unsigned& lo) {
  unsigned h;
  asm("v_cvt_pk_bf16_f32 %0, %1, %2" : "=v"(h) : "v"(a), "v"(b));
  float ha = __uint_as_float(h << 16);
  float hb = __uint_as_float(h & 0xFFFF0000u);
  float la = a - ha, lb = b - hb;
  unsigned l;
  asm("v_cvt_pk_bf16_f32 %0, %1, %2" : "=v"(l) : "v"(la), "v"(lb));
  hi = h; lo = l;
}

// Weight prep: fold per-head 3x3 rotation into Wq (with log2e/sqrt(3) scale)
// and Wk (fp32, exact), concat [WqR|WkR|Wv] as 576x192, split every matrix
// (incl. Wo) into bf16 hi + lo residual for split-bf16 MFMA GEMMs.
__global__ __launch_bounds__(256) void fold_split_k(
    const float* __restrict__ Wq, const float* __restrict__ Wk,
    const float* __restrict__ Wv, const float* __restrict__ Wo,
    const float* __restrict__ rot,
    __hip_bfloat16* __restrict__ Wch, __hip_bfloat16* __restrict__ Wcl,
    __hip_bfloat16* __restrict__ Woh, __hip_bfloat16* __restrict__ Wol)
{
  int t = blockIdx.x * 256 + threadIdx.x;
  float val;
  __hip_bfloat16 *ph, *pl;
  int idx;
  if (t < 576 * EE) {
    int o = t / EE, e = t - o * EE;
    int s3 = o / 192, oo = o - s3 * 192;
    int h = oo / 3, ep = oo - h * 3;
    if (s3 == 2) {
      val = Wv[(size_t)oo * EE + e];
    } else {
      const float* W = s3 ? Wk : Wq;
      float acc = 0.f;
#pragma unroll
      for (int d = 0; d < 3; ++d)
        acc += rot[h * 9 + d * 3 + ep] * W[(size_t)(h * 3 + d) * EE + e];
      val = acc * (s3 ? 1.0f : 0.8329876360019913f);  // log2(e)/sqrt(3) for Q
    }
    ph = Wch; pl = Wcl; idx = t;
  } else {
    int u = t - 576 * EE;
    if (u >= EE * EE) return;
    val = Wo[u]; ph = Woh; pl = Wol; idx = u;
  }
  __hip_bfloat16 hi = __float2bfloat16(val);
  float lo = val - __bfloat162float(hi);
  ph[idx] = hi;
  pl[idx] = __float2bfloat16(lo);
}

// QKV projection, split-bf16 MFMA: C(4096x576) = x(4096x192) @ Wcat^T.
// Block = 64x64 output tile, 4 waves (2x2 of 32x32), K chunked by 64.
// acc = Ah*Bh + Al*Bh + Ah*Bl (lo*lo dropped, ~2^-18) -> fp32-grade result.
// Q,K -> bf16 (B*H,S,4) slot3=0; V -> bf16 col-major (B*H,3,S).
__global__ __launch_bounds__(256) void gemm_qkv_k(
    const float* __restrict__ x,
    const unsigned short* __restrict__ Wch, const unsigned short* __restrict__ Wcl,
    __hip_bfloat16* __restrict__ Qf, __hip_bfloat16* __restrict__ Kf,
    __hip_bfloat16* __restrict__ Vc)
{
  __shared__ __align__(16) short xsh[64][72], xsl[64][72];
  __shared__ __align__(16) short wsh[64][72], wsl[64][72];
  int colBase = blockIdx.x * 64;   // col-group over 576 outs
  int rowBase = blockIdx.y * 64;   // row-group over 4096 rows
  int t = threadIdx.x;
  int lane = t & 63, w = t >> 6;
  int wr = w >> 1, wc = w & 1;
  int l31 = lane & 31, lh = lane >> 5;

  const fx16 zc = {0,0,0,0, 0,0,0,0, 0,0,0,0, 0,0,0,0};
  fx16 acc = zc;

  int srow = t >> 2, sk = (t & 3) * 16;

  for (int kk = 0; kk < 3; ++kk) {
    const float4* xg = (const float4*)&x[(size_t)(rowBase + srow) * EE + kk * 64 + sk];
    float4 v0 = xg[0], v1 = xg[1], v2 = xg[2], v3 = xg[3];
    const uint4* whg = (const uint4*)&Wch[(size_t)(colBase + srow) * EE + kk * 64 + sk];
    const uint4* wlg = (const uint4*)&Wcl[(size_t)(colBase + srow) * EE + kk * 64 + sk];
    uint4 wh0 = whg[0], wh1 = whg[1], wl0 = wlg[0], wl1 = wlg[1];

    unsigned hu[8], lu[8];
    split2(v0.x, v0.y, hu[0], lu[0]); split2(v0.z, v0.w, hu[1], lu[1]);
    split2(v1.x, v1.y, hu[2], lu[2]); split2(v1.z, v1.w, hu[3], lu[3]);
    split2(v2.x, v2.y, hu[4], lu[4]); split2(v2.z, v2.w, hu[5], lu[5]);
    split2(v3.x, v3.y, hu[6], lu[6]); split2(v3.z, v3.w, hu[7], lu[7]);

    __syncthreads();  // previous chunk's MFMA reads complete
    *(uint4*)&xsh[srow][sk]     = make_uint4(hu[0], hu[1], hu[2], hu[3]);
    *(uint4*)&xsh[srow][sk + 8] = make_uint4(hu[4], hu[5], hu[6], hu[7]);
    *(uint4*)&xsl[srow][sk]     = make_uint4(lu[0], lu[1], lu[2], lu[3]);
    *(uint4*)&xsl[srow][sk + 8] = make_uint4(lu[4], lu[5], lu[6], lu[7]);
    *(uint4*)&wsh[srow][sk]     = wh0;
    *(uint4*)&wsh[srow][sk + 8] = wh1;
    *(uint4*)&wsl[srow][sk]     = wl0;
    *(uint4*)&wsl[srow][sk + 8] = wl1;
    __syncthreads();

#pragma unroll
    for (int ks = 0; ks < 4; ++ks) {
      int ac = ks * 16 + lh * 8;
      U4B Ah, Al, Bh, Bl;
      Ah.u = *(const uint4*)&xsh[wr * 32 + l31][ac];
      Al.u = *(const uint4*)&xsl[wr * 32 + l31][ac];
      Bh.u = *(const uint4*)&wsh[wc * 32 + l31][ac];
      Bl.u = *(const uint4*)&wsl[wc * 32 + l31][ac];
      acc = __builtin_amdgcn_mfma_f32_32x32x16_bf16(Ah.s, Bh.s, acc, 0, 0, 0);
      acc = __builtin_amdgcn_mfma_f32_32x32x16_bf16(Al.s, Bh.s, acc, 0, 0, 0);
      acc = __builtin_amdgcn_mfma_f32_32x32x16_bf16(Ah.s, Bl.s, acc, 0, 0, 0);
    }
  }

  // epilogue: C/D layout col=l31, row=(r&3)+8*(r>>2)+4*lh
  int o = colBase + wc * 32 + l31;
  int s3 = o / 192, oo = o - s3 * 192;
  int hh = oo / 3, d = oo - hh * 3;
#pragma unroll
  for (int r = 0; r < 16; ++r) {
    int row = rowBase + wr * 32 + (r & 3) + 8 * (r >> 2) + 4 * lh;
    int b = row >> 10, s = row & (SS - 1);
    size_t bh = (size_t)(b * HH + hh);
    float v = acc[r];
    if (s3 == 0) {
      Qf[(bh * SS + s) * 4 + d] = __float2bfloat16(v);
      if (d == 2) Qf[(bh * SS + s) * 4 + 3] = __float2bfloat16(0.0f);
    } else if (s3 == 1) {
      Kf[(bh * SS + s) * 4 + d] = __float2bfloat16(v);
      if (d == 2) Kf[(bh * SS + s) * 4 + 3] = __float2bfloat16(0.0f);
    } else {
      Vc[bh * (3 * SS) + (size_t)d * SS + s] = __float2bfloat16(v);
    }
  }
}

// MFMA attention (r9-proven body). Block = (head, query-eighth): 2048 blocks.
// Swapped QK^T (A=K, B=Q) -> D[key][query]; B(=Q) zero for k>=3 so K is
// (S,4) bf16, A-frag {k-pair,0,0}. exp2 in-register, cvt_pk +
// permlane32_swap -> PV A-frags; V ones-column yields l via the PV MFMA.
// Epilogue writes AO as bf16 hi+lo split (producer-side split: bit-identical
// to the old consumer-side split2 in gemm_out).
// NOTE: exactly ONE S-tuple live at a time — the dual-chain variants
// (r10/r11, two live S tuples) deterministically corrupted S.
__global__ __launch_bounds__(256, 4) void attn_k(
    const unsigned short* __restrict__ Qfg, const unsigned short* __restrict__ Kfg,
    const unsigned short* __restrict__ Vcg,
    __hip_bfloat16* __restrict__ AOh, __hip_bfloat16* __restrict__ AOl)
{
  __shared__ __align__(16) short KfL[1024 * 4];   // 8 KB: [key][k0 k1 k2 0]
  __shared__ __align__(16) short VcL[4 * 1040];   // 8.1 KB: rows v0 v1 v2 ones
  int bh = blockIdx.x & 255;       // eighth-major: same-head blocks 256 apart (same XCD)
  int eighth = blockIdx.x >> 8;
  int b = bh >> 6, h = bh & 63;

  const uint2* ksrc = (const uint2*)Kfg + (size_t)bh * 1024;
  uint2* kdst = (uint2*)KfL;
  for (int i = threadIdx.x; i < 1024; i += 256) kdst[i] = ksrc[i];
  const uint4* vsrc = (const uint4*)Vcg + (size_t)bh * 384;
  for (int i = threadIdx.x; i < 384; i += 256) {
    int r = i >> 7, cq = i & 127;
    *(uint4*)(VcL + r * 1040 + cq * 8) = vsrc[i];
  }
  {
    unsigned v1 = 0x3F803F80u;
    for (int i = threadIdx.x; i < 128; i += 256)
      *(uint4*)(VcL + 3 * 1040 + i * 8) = make_uint4(v1, v1, v1, v1);
  }
  __syncthreads();

  int lane = threadIdx.x & 63, w = threadIdx.x >> 6;
  int h32 = lane >> 5;
  int col = lane & 31;
  int q32 = eighth * 128 + w * 32;

  // Q B-frag: direct bf16 pair load (h1 lanes = zero half of K-dim)
  uint2 qq = *(const uint2*)(Qfg + ((size_t)bh * SS + q32 + col) * 4);
  U4B bq; bq.u = make_uint4(h32 ? 0u : qq.x, h32 ? 0u : qq.y, 0u, 0u);

  const fx16 zc = {0,0,0,0, 0,0,0,0, 0,0,0,0, 0,0,0,0};
  fx16 accPV = zc;
  int vbase = (col & 3) * 1040 + 8 * h32;

  for (int kt = 0; kt < 32; ++kt) {
    uint2 kk = *(const uint2*)(KfL + (size_t)(kt * 32 + col) * 4);
    U4B ak; ak.u = make_uint4(kk.x, kk.y, 0u, 0u);
    U4B bv1; bv1.u = *(const uint4*)(VcL + vbase + kt * 32);
    U4B bv2; bv2.u = *(const uint4*)(VcL + vbase + kt * 32 + 16);

    fx16 S = __builtin_amdgcn_mfma_f32_32x32x16_bf16(ak.s, bq.s, zc, 0, 0, 0);
    asm("" : "+v"(S));
#pragma unroll
    for (int i = 0; i < 16; ++i) S[i] = fast_exp2(S[i]);
    unsigned u0, u1, u2, u3, u4, u5, u6, u7;
    asm("v_cvt_pk_bf16_f32 %0, %1, %2" : "=v"(u0) : "v"(S[0]),  "v"(S[1]));
    asm("v_cvt_pk_bf16_f32 %0, %1, %2" : "=v"(u1) : "v"(S[2]),  "v"(S[3]));
    asm("v_cvt_pk_bf16_f32 %0, %1, %2" : "=v"(u2) : "v"(S[4]),  "v"(S[5]));
    asm("v_cvt_pk_bf16_f32 %0, %1, %2" : "=v"(u3) : "v"(S[6]),  "v"(S[7]));
    asm("v_cvt_pk_bf16_f32 %0, %1, %2" : "=v"(u4) : "v"(S[8]),  "v"(S[9]));
    asm("v_cvt_pk_bf16_f32 %0, %1, %2" : "=v"(u5) : "v"(S[10]), "v"(S[11]));
    asm("v_cvt_pk_bf16_f32 %0, %1, %2" : "=v"(u6) : "v"(S[12]), "v"(S[13]));
    asm("v_cvt_pk_bf16_f32 %0, %1, %2" : "=v"(u7) : "v"(S[14]), "v"(S[15]));
    asm("v_permlane32_swap_b32 %0, %1" : "+v"(u0), "+v"(u2));
    asm("v_permlane32_swap_b32 %0, %1" : "+v"(u1), "+v"(u3));
    asm("v_permlane32_swap_b32 %0, %1" : "+v"(u4), "+v"(u6));
    asm("v_permlane32_swap_b32 %0, %1" : "+v"(u5), "+v"(u7));
    U4B p1; p1.u = make_uint4(u0, u1, u2, u3);
    U4B p2; p2.u = make_uint4(u4, u5, u6, u7);
    accPV = __builtin_amdgcn_mfma_f32_32x32x16_bf16(p1.s, bv1.s, accPV, 0, 0, 0);
    accPV = __builtin_amdgcn_mfma_f32_32x32x16_bf16(p2.s, bv2.s, accPV, 0, 0, 0);
  }

  // Epilogue: D_pv[query row][col]: col 0-2 = o, col 3 = l. Normalize, split
  // to bf16 hi+lo (same math gemm_out's split2 used), write.
  int base3 = (lane & 32) | 3;
  float inv[16];
#pragma unroll
  for (int rg = 0; rg < 16; ++rg)
    inv[rg] = __shfl(fast_rcp(accPV[rg]), base3, 64);
  if (col < 3) {
#pragma unroll
    for (int rg = 0; rg < 16; ++rg) {
      int row = (rg & 3) + 8 * (rg >> 2) + 4 * h32;
      float v = accPV[rg] * inv[rg];
      __hip_bfloat16 hi = __float2bfloat16(v);
      float lo = v - __bfloat162float(hi);
      size_t idx = ((size_t)(b * SS + q32 + row)) * EE + h * 3 + col;
      AOh[idx] = hi;
      AOl[idx] = __float2bfloat16(lo);
    }
  }
}

// Output projection, split-bf16 MFMA: out(4096x192) = AO @ Wo^T. grid (3,64).
// x side arrives pre-split (AOh/AOl from attn) -> pure uint4 staging, no VALU.
__global__ __launch_bounds__(256) void gemm_out_k(
    const unsigned short* __restrict__ AOh, const unsigned short* __restrict__ AOl,
    const unsigned short* __restrict__ Woh, const unsigned short* __restrict__ Wol,
    float* __restrict__ out)
{
  __shared__ __align__(16) short xsh[64][72], xsl[64][72];
  __shared__ __align__(16) short wsh[64][72], wsl[64][72];
  int colBase = blockIdx.x * 64;
  int rowBase = blockIdx.y * 64;
  int t = threadIdx.x;
  int lane = t & 63, w = t >> 6;
  int wr = w >> 1, wc = w & 1;
  int l31 = lane & 31, lh = lane >> 5;

  const fx16 zc = {0,0,0,0, 0,0,0,0, 0,0,0,0, 0,0,0,0};
  fx16 acc = zc;

  int srow = t >> 2, sk = (t & 3) * 16;

  for (int kk = 0; kk < 3; ++kk) {
    const uint4* xhg = (const uint4*)&AOh[(size_t)(rowBase + srow) * EE + kk * 64 + sk];
    const uint4* xlg = (const uint4*)&AOl[(size_t)(rowBase + srow) * EE + kk * 64 + sk];
    uint4 a0 = xhg[0], a1 = xhg[1], b0 = xlg[0], b1 = xlg[1];
    const uint4* whg = (const uint4*)&Woh[(size_t)(colBase + srow) * EE + kk * 64 + sk];
    const uint4* wlg = (const uint4*)&Wol[(size_t)(colBase + srow) * EE + kk * 64 + sk];
    uint4 wh0 = whg[0], wh1 = whg[1], wl0 = wlg[0], wl1 = wlg[1];

    __syncthreads();
    *(uint4*)&xsh[srow][sk]     = a0;
    *(uint4*)&xsh[srow][sk + 8] = a1;
    *(uint4*)&xsl[srow][sk]     = b0;
    *(uint4*)&xsl[srow][sk + 8] = b1;
    *(uint4*)&wsh[srow][sk]     = wh0;
    *(uint4*)&wsh[srow][sk + 8] = wh1;
    *(uint4*)&wsl[srow][sk]     = wl0;
    *(uint4*)&wsl[srow][sk + 8] = wl1;
    __syncthreads();

#pragma unroll
    for (int ks = 0; ks < 4; ++ks) {
      int ac = ks * 16 + lh * 8;
      U4B Ah, Al, Bh, Bl;
      Ah.u = *(const uint4*)&xsh[wr * 32 + l31][ac];
      Al.u = *(const uint4*)&xsl[wr * 32 + l31][ac];
      Bh.u = *(const uint4*)&wsh[wc * 32 + l31][ac];
      Bl.u = *(const uint4*)&wsl[wc * 32 + l31][ac];
      acc = __builtin_amdgcn_mfma_f32_32x32x16_bf16(Ah.s, Bh.s, acc, 0, 0, 0);
      acc = __builtin_amdgcn_mfma_f32_32x32x16_bf16(Al.s, Bh.s, acc, 0, 0, 0);
      acc = __builtin_amdgcn_mfma_f32_32x32x16_bf16(Ah.s, Bl.s, acc, 0, 0, 0);
    }
  }

  int o = colBase + wc * 32 + l31;
#pragma unroll
  for (int r = 0; r < 16; ++r) {
    int row = rowBase + wr * 32 + (r & 3) + 8 * (r >> 2) + 4 * lh;
    out[(size_t)row * EE + o] = acc[r];
  }
}

extern "C" void kernel_launch(void* const* d_in, const int* in_sizes, int n_in,
                              void* d_out, int out_size, void* d_ws, size_t ws_size,
                              hipStream_t stream) {
  const float* x   = (const float*)d_in[0];
  const float* Wq  = (const float*)d_in[1];
  const float* Wk  = (const float*)d_in[2];
  const float* Wv  = (const float*)d_in[3];
  const float* Wo  = (const float*)d_in[4];
  const float* rot = (const float*)d_in[5];
  float* ws  = (float*)d_ws;
  unsigned short* Qf  = (unsigned short*)(ws + OFF_QF);
  unsigned short* Kf  = (unsigned short*)(ws + OFF_KF);
  unsigned short* Vc  = (unsigned short*)(ws + OFF_VC);
  unsigned short* AOh = (unsigned short*)(ws + OFF_AOH);
  unsigned short* AOl = (unsigned short*)(ws + OFF_AOL);
  unsigned short* Wch = (unsigned short*)(ws + OFF_WCH);
  unsigned short* Wcl = (unsigned short*)(ws + OFF_WCL);
  unsigned short* Woh = (unsigned short*)(ws + OFF_WOH);
  unsigned short* Wol = (unsigned short*)(ws + OFF_WOL);
  float* out = (float*)d_out;

  fold_split_k<<<dim3((576 * EE + EE * EE) / 256), 256, 0, stream>>>(
      Wq, Wk, Wv, Wo, rot,
      (__hip_bfloat16*)Wch, (__hip_bfloat16*)Wcl,
      (__hip_bfloat16*)Woh, (__hip_bfloat16*)Wol);
  gemm_qkv_k<<<dim3(9, 64), 256, 0, stream>>>(x, Wch, Wcl,
                                              (__hip_bfloat16*)Qf, (__hip_bfloat16*)Kf,
                                              (__hip_bfloat16*)Vc);
  attn_k<<<dim3(BH * 8), 256, 0, stream>>>(Qf, Kf, Vc,
                                           (__hip_bfloat16*)AOh, (__hip_bfloat16*)AOl);
  gemm_out_k<<<dim3(3, 64), 256, 0, stream>>>(AOh, AOl, Woh, Wol, out);
}

// Round 13
// 66.536 us; speedup vs baseline: 1.0029x; 1.0029x over previous
//
#include <hip/hip_runtime.h>
#include <hip/hip_bf16.h>

// Problem dims
#define BB 4
#define SS 1024
#define EE 192
#define HH 64
// D = 3 (head dim)

constexpr int BH = BB * HH;  // 256

typedef __attribute__((ext_vector_type(8))) short bs8;    // 8 bf16 = 4 VGPR (MFMA A/B frag)
typedef __attribute__((ext_vector_type(16))) float fx16;  // MFMA C/D frag
union U4B { uint4 u; bs8 s; };

// ws layout (float units)
constexpr size_t OFF_QF  = 0;                             // (B*H,S,4) bf16: q0 q1 q2 0
constexpr size_t OFF_KF  = OFF_QF  + (size_t)BH*SS*2;     // (B*H,S,4) bf16: k0 k1 k2 0
constexpr size_t OFF_VC  = OFF_KF  + (size_t)BH*SS*2;     // (B*H,3,S) bf16 col-major
constexpr size_t OFF_AOH = OFF_VC  + (size_t)BH*SS*3/2;   // (B,S,E) bf16 hi
constexpr size_t OFF_AOL = OFF_AOH + (size_t)BB*SS*EE/2;  // (B,S,E) bf16 lo
constexpr size_t OFF_WCH = OFF_AOL + (size_t)BB*SS*EE/2;  // (576,192) bf16 hi (WqR|WkR|Wv)
constexpr size_t OFF_WCL = OFF_WCH + (size_t)576*EE/2;    // lo
constexpr size_t OFF_WOH = OFF_WCL + (size_t)576*EE/2;    // (192,192) bf16 hi (Wo)
constexpr size_t OFF_WOL = OFF_WOH + (size_t)EE*EE/2;     // lo

static __device__ __forceinline__ float fast_exp2(float x) {
#if __has_builtin(__builtin_amdgcn_exp2f)
  return __builtin_amdgcn_exp2f(x);
#else
  return exp2f(x);
#endif
}
static __device__ __forceinline__ float fast_rcp(float x) {
#if __has_builtin(__builtin_amdgcn_rcpf)
  return __builtin_amdgcn_rcpf(x);
#else
  return 1.0f / x;
#endif
}

// split a pair of fp32 into packed bf16 hi + bf16 lo (lo = residual)
static __device__ __forceinline__ void split2(float a, float b, unsigned& hi, unsigned& lo) {
  unsigned h;
  asm("v_cvt_pk_bf16_f32 %0, %1, %2" : "=v"(h) : "v"(a), "v"(b));
  float ha = __uint_as_float(h << 16);
  float hb = __uint_as_float(h & 0xFFFF0000u);
  float la = a - ha, lb = b - hb;
  unsigned l;
  asm("v_cvt_pk_bf16_f32 %0, %1, %2" : "=v"(l) : "v"(la), "v"(lb));
  hi = h; lo = l;
}

// Weight prep: fold per-head 3x3 rotation into Wq (with log2e/sqrt(3) scale)
// and Wk (fp32, exact), concat [WqR|WkR|Wv] as 576x192, split every matrix
// (incl. Wo) into bf16 hi + lo residual for split-bf16 MFMA GEMMs.
__global__ __launch_bounds__(256) void fold_split_k(
    const float* __restrict__ Wq, const float* __restrict__ Wk,
    const float* __restrict__ Wv, const float* __restrict__ Wo,
    const float* __restrict__ rot,
    __hip_bfloat16* __restrict__ Wch, __hip_bfloat16* __restrict__ Wcl,
    __hip_bfloat16* __restrict__ Woh, __hip_bfloat16* __restrict__ Wol)
{
  int t = blockIdx.x * 256 + threadIdx.x;
  float val;
  __hip_bfloat16 *ph, *pl;
  int idx;
  if (t < 576 * EE) {
    int o = t / EE, e = t - o * EE;
    int s3 = o / 192, oo = o - s3 * 192;
    int h = oo / 3, ep = oo - h * 3;
    if (s3 == 2) {
      val = Wv[(size_t)oo * EE + e];
    } else {
      const float* W = s3 ? Wk : Wq;
      float acc = 0.f;
#pragma unroll
      for (int d = 0; d < 3; ++d)
        acc += rot[h * 9 + d * 3 + ep] * W[(size_t)(h * 3 + d) * EE + e];
      val = acc * (s3 ? 1.0f : 0.8329876360019913f);  // log2(e)/sqrt(3) for Q
    }
    ph = Wch; pl = Wcl; idx = t;
  } else {
    int u = t - 576 * EE;
    if (u >= EE * EE) return;
    val = Wo[u]; ph = Woh; pl = Wol; idx = u;
  }
  __hip_bfloat16 hi = __float2bfloat16(val);
  float lo = val - __bfloat162float(hi);
  ph[idx] = hi;
  pl[idx] = __float2bfloat16(lo);
}

// QKV projection, split-bf16 MFMA: C(4096x576) = x(4096x192) @ Wcat^T.
// Block = 64x64 output tile, 4 waves (2x2 of 32x32), K chunked by 64.
// acc = Ah*Bh + Al*Bh + Ah*Bl (lo*lo dropped, ~2^-18) -> fp32-grade result.
// Q,K -> bf16 (B*H,S,4) slot3=0; V -> bf16 col-major (B*H,3,S).
__global__ __launch_bounds__(256) void gemm_qkv_k(
    const float* __restrict__ x,
    const unsigned short* __restrict__ Wch, const unsigned short* __restrict__ Wcl,
    __hip_bfloat16* __restrict__ Qf, __hip_bfloat16* __restrict__ Kf,
    __hip_bfloat16* __restrict__ Vc)
{
  __shared__ __align__(16) short xsh[64][72], xsl[64][72];
  __shared__ __align__(16) short wsh[64][72], wsl[64][72];
  int colBase = blockIdx.x * 64;   // col-group over 576 outs
  int rowBase = blockIdx.y * 64;   // row-group over 4096 rows
  int t = threadIdx.x;
  int lane = t & 63, w = t >> 6;
  int wr = w >> 1, wc = w & 1;
  int l31 = lane & 31, lh = lane >> 5;

  const fx16 zc = {0,0,0,0, 0,0,0,0, 0,0,0,0, 0,0,0,0};
  fx16 acc = zc;

  int srow = t >> 2, sk = (t & 3) * 16;

  for (int kk = 0; kk < 3; ++kk) {
    const float4* xg = (const float4*)&x[(size_t)(rowBase + srow) * EE + kk * 64 + sk];
    float4 v0 = xg[0], v1 = xg[1], v2 = xg[2], v3 = xg[3];
    const uint4* whg = (const uint4*)&Wch[(size_t)(colBase + srow) * EE + kk * 64 + sk];
    const uint4* wlg = (const uint4*)&Wcl[(size_t)(colBase + srow) * EE + kk * 64 + sk];
    uint4 wh0 = whg[0], wh1 = whg[1], wl0 = wlg[0], wl1 = wlg[1];

    unsigned hu[8], lu[8];
    split2(v0.x, v0.y, hu[0], lu[0]); split2(v0.z, v0.w, hu[1], lu[1]);
    split2(v1.x, v1.y, hu[2], lu[2]); split2(v1.z, v1.w, hu[3], lu[3]);
    split2(v2.x, v2.y, hu[4], lu[4]); split2(v2.z, v2.w, hu[5], lu[5]);
    split2(v3.x, v3.y, hu[6], lu[6]); split2(v3.z, v3.w, hu[7], lu[7]);

    __syncthreads();  // previous chunk's MFMA reads complete
    *(uint4*)&xsh[srow][sk]     = make_uint4(hu[0], hu[1], hu[2], hu[3]);
    *(uint4*)&xsh[srow][sk + 8] = make_uint4(hu[4], hu[5], hu[6], hu[7]);
    *(uint4*)&xsl[srow][sk]     = make_uint4(lu[0], lu[1], lu[2], lu[3]);
    *(uint4*)&xsl[srow][sk + 8] = make_uint4(lu[4], lu[5], lu[6], lu[7]);
    *(uint4*)&wsh[srow][sk]     = wh0;
    *(uint4*)&wsh[srow][sk + 8] = wh1;
    *(uint4*)&wsl[srow][sk]     = wl0;
    *(uint4*)&wsl[srow][sk + 8] = wl1;
    __syncthreads();

#pragma unroll
    for (int ks = 0; ks < 4; ++ks) {
      int ac = ks * 16 + lh * 8;
      U4B Ah, Al, Bh, Bl;
      Ah.u = *(const uint4*)&xsh[wr * 32 + l31][ac];
      Al.u = *(const uint4*)&xsl[wr * 32 + l31][ac];
      Bh.u = *(const uint4*)&wsh[wc * 32 + l31][ac];
      Bl.u = *(const uint4*)&wsl[wc * 32 + l31][ac];
      acc = __builtin_amdgcn_mfma_f32_32x32x16_bf16(Ah.s, Bh.s, acc, 0, 0, 0);
      acc = __builtin_amdgcn_mfma_f32_32x32x16_bf16(Al.s, Bh.s, acc, 0, 0, 0);
      acc = __builtin_amdgcn_mfma_f32_32x32x16_bf16(Ah.s, Bl.s, acc, 0, 0, 0);
    }
  }

  // epilogue: C/D layout col=l31, row=(r&3)+8*(r>>2)+4*lh
  int o = colBase + wc * 32 + l31;
  int s3 = o / 192, oo = o - s3 * 192;
  int hh = oo / 3, d = oo - hh * 3;
#pragma unroll
  for (int r = 0; r < 16; ++r) {
    int row = rowBase + wr * 32 + (r & 3) + 8 * (r >> 2) + 4 * lh;
    int b = row >> 10, s = row & (SS - 1);
    size_t bh = (size_t)(b * HH + hh);
    float v = acc[r];
    if (s3 == 0) {
      Qf[(bh * SS + s) * 4 + d] = __float2bfloat16(v);
      if (d == 2) Qf[(bh * SS + s) * 4 + 3] = __float2bfloat16(0.0f);
    } else if (s3 == 1) {
      Kf[(bh * SS + s) * 4 + d] = __float2bfloat16(v);
      if (d == 2) Kf[(bh * SS + s) * 4 + 3] = __float2bfloat16(0.0f);
    } else {
      Vc[bh * (3 * SS) + (size_t)d * SS + s] = __float2bfloat16(v);
    }
  }
}

// MFMA attention (r9-proven body). Block = (head, query-eighth): 2048 blocks.
// Swapped QK^T (A=K, B=Q) -> D[key][query]; B(=Q) zero for k>=3 so K is
// (S,4) bf16, A-frag {k-pair,0,0}. exp2 in-register, cvt_pk +
// permlane32_swap -> PV A-frags; V ones-column yields l via the PV MFMA.
// Epilogue writes AO as bf16 hi+lo split (producer-side split: bit-identical
// to the old consumer-side split2 in gemm_out).
// NOTE: exactly ONE S-tuple live at a time — the dual-chain variants
// (r10/r11, two live S tuples) deterministically corrupted S.
__global__ __launch_bounds__(256, 4) void attn_k(
    const unsigned short* __restrict__ Qfg, const unsigned short* __restrict__ Kfg,
    const unsigned short* __restrict__ Vcg,
    __hip_bfloat16* __restrict__ AOh, __hip_bfloat16* __restrict__ AOl)
{
  __shared__ __align__(16) short KfL[1024 * 4];   // 8 KB: [key][k0 k1 k2 0]
  __shared__ __align__(16) short VcL[4 * 1040];   // 8.1 KB: rows v0 v1 v2 ones
  int bh = blockIdx.x & 255;       // eighth-major: same-head blocks 256 apart (same XCD)
  int eighth = blockIdx.x >> 8;
  int b = bh >> 6, h = bh & 63;

  const uint2* ksrc = (const uint2*)Kfg + (size_t)bh * 1024;
  uint2* kdst = (uint2*)KfL;
  for (int i = threadIdx.x; i < 1024; i += 256) kdst[i] = ksrc[i];
  const uint4* vsrc = (const uint4*)Vcg + (size_t)bh * 384;
  for (int i = threadIdx.x; i < 384; i += 256) {
    int r = i >> 7, cq = i & 127;
    *(uint4*)(VcL + r * 1040 + cq * 8) = vsrc[i];
  }
  {
    unsigned v1 = 0x3F803F80u;
    for (int i = threadIdx.x; i < 128; i += 256)
      *(uint4*)(VcL + 3 * 1040 + i * 8) = make_uint4(v1, v1, v1, v1);
  }
  __syncthreads();

  int lane = threadIdx.x & 63, w = threadIdx.x >> 6;
  int h32 = lane >> 5;
  int col = lane & 31;
  int q32 = eighth * 128 + w * 32;

  // Q B-frag: direct bf16 pair load (h1 lanes = zero half of K-dim)
  uint2 qq = *(const uint2*)(Qfg + ((size_t)bh * SS + q32 + col) * 4);
  U4B bq; bq.u = make_uint4(h32 ? 0u : qq.x, h32 ? 0u : qq.y, 0u, 0u);

  const fx16 zc = {0,0,0,0, 0,0,0,0, 0,0,0,0, 0,0,0,0};
  fx16 accPV = zc;
  int vbase = (col & 3) * 1040 + 8 * h32;

  for (int kt = 0; kt < 32; ++kt) {
    uint2 kk = *(const uint2*)(KfL + (size_t)(kt * 32 + col) * 4);
    U4B ak; ak.u = make_uint4(kk.x, kk.y, 0u, 0u);
    U4B bv1; bv1.u = *(const uint4*)(VcL + vbase + kt * 32);
    U4B bv2; bv2.u = *(const uint4*)(VcL + vbase + kt * 32 + 16);

    fx16 S = __builtin_amdgcn_mfma_f32_32x32x16_bf16(ak.s, bq.s, zc, 0, 0, 0);
    asm("" : "+v"(S));
#pragma unroll
    for (int i = 0; i < 16; ++i) S[i] = fast_exp2(S[i]);
    unsigned u0, u1, u2, u3, u4, u5, u6, u7;
    asm("v_cvt_pk_bf16_f32 %0, %1, %2" : "=v"(u0) : "v"(S[0]),  "v"(S[1]));
    asm("v_cvt_pk_bf16_f32 %0, %1, %2" : "=v"(u1) : "v"(S[2]),  "v"(S[3]));
    asm("v_cvt_pk_bf16_f32 %0, %1, %2" : "=v"(u2) : "v"(S[4]),  "v"(S[5]));
    asm("v_cvt_pk_bf16_f32 %0, %1, %2" : "=v"(u3) : "v"(S[6]),  "v"(S[7]));
    asm("v_cvt_pk_bf16_f32 %0, %1, %2" : "=v"(u4) : "v"(S[8]),  "v"(S[9]));
    asm("v_cvt_pk_bf16_f32 %0, %1, %2" : "=v"(u5) : "v"(S[10]), "v"(S[11]));
    asm("v_cvt_pk_bf16_f32 %0, %1, %2" : "=v"(u6) : "v"(S[12]), "v"(S[13]));
    asm("v_cvt_pk_bf16_f32 %0, %1, %2" : "=v"(u7) : "v"(S[14]), "v"(S[15]));
    asm("v_permlane32_swap_b32 %0, %1" : "+v"(u0), "+v"(u2));
    asm("v_permlane32_swap_b32 %0, %1" : "+v"(u1), "+v"(u3));
    asm("v_permlane32_swap_b32 %0, %1" : "+v"(u4), "+v"(u6));
    asm("v_permlane32_swap_b32 %0, %1" : "+v"(u5), "+v"(u7));
    U4B p1; p1.u = make_uint4(u0, u1, u2, u3);
    U4B p2; p2.u = make_uint4(u4, u5, u6, u7);
    accPV = __builtin_amdgcn_mfma_f32_32x32x16_bf16(p1.s, bv1.s, accPV, 0, 0, 0);
    accPV = __builtin_amdgcn_mfma_f32_32x32x16_bf16(p2.s, bv2.s, accPV, 0, 0, 0);
  }

  // Epilogue: D_pv[query row][col]: col 0-2 = o, col 3 = l. Normalize, split
  // to bf16 hi+lo (same math gemm_out's split2 used), write.
  int base3 = (lane & 32) | 3;
  float inv[16];
#pragma unroll
  for (int rg = 0; rg < 16; ++rg)
    inv[rg] = __shfl(fast_rcp(accPV[rg]), base3, 64);
  if (col < 3) {
#pragma unroll
    for (int rg = 0; rg < 16; ++rg) {
      int row = (rg & 3) + 8 * (rg >> 2) + 4 * h32;
      float v = accPV[rg] * inv[rg];
      __hip_bfloat16 hi = __float2bfloat16(v);
      float lo = v - __bfloat162float(hi);
      size_t idx = ((size_t)(b * SS + q32 + row)) * EE + h * 3 + col;
      AOh[idx] = hi;
      AOl[idx] = __float2bfloat16(lo);
    }
  }
}

// Output projection, split-bf16 MFMA: out(4096x192) = AO @ Wo^T. grid (3,64).
// x side arrives pre-split (AOh/AOl from attn) -> pure uint4 staging, no VALU.
__global__ __launch_bounds__(256) void gemm_out_k(
    const unsigned short* __restrict__ AOh, const unsigned short* __restrict__ AOl,
    const unsigned short* __restrict__ Woh, const unsigned short* __restrict__ Wol,
    float* __restrict__ out)
{
  __shared__ __align__(16) short xsh[64][72], xsl[64][72];
  __shared__ __align__(16) short wsh[64][72], wsl[64][72];
  int colBase = blockIdx.x * 64;
  int rowBase = blockIdx.y * 64;
  int t = threadIdx.x;
  int lane = t & 63, w = t >> 6;
  int wr = w >> 1, wc = w & 1;
  int l31 = lane & 31, lh = lane >> 5;

  const fx16 zc = {0,0,0,0, 0,0,0,0, 0,0,0,0, 0,0,0,0};
  fx16 acc = zc;

  int srow = t >> 2, sk = (t & 3) * 16;

  for (int kk = 0; kk < 3; ++kk) {
    const uint4* xhg = (const uint4*)&AOh[(size_t)(rowBase + srow) * EE + kk * 64 + sk];
    const uint4* xlg = (const uint4*)&AOl[(size_t)(rowBase + srow) * EE + kk * 64 + sk];
    uint4 a0 = xhg[0], a1 = xhg[1], b0 = xlg[0], b1 = xlg[1];
    const uint4* whg = (const uint4*)&Woh[(size_t)(colBase + srow) * EE + kk * 64 + sk];
    const uint4* wlg = (const uint4*)&Wol[(size_t)(colBase + srow) * EE + kk * 64 + sk];
    uint4 wh0 = whg[0], wh1 = whg[1], wl0 = wlg[0], wl1 = wlg[1];

    __syncthreads();
    *(uint4*)&xsh[srow][sk]     = a0;
    *(uint4*)&xsh[srow][sk + 8] = a1;
    *(uint4*)&xsl[srow][sk]     = b0;
    *(uint4*)&xsl[srow][sk + 8] = b1;
    *(uint4*)&wsh[srow][sk]     = wh0;
    *(uint4*)&wsh[srow][sk + 8] = wh1;
    *(uint4*)&wsl[srow][sk]     = wl0;
    *(uint4*)&wsl[srow][sk + 8] = wl1;
    __syncthreads();

#pragma unroll
    for (int ks = 0; ks < 4; ++ks) {
      int ac = ks * 16 + lh * 8;
      U4B Ah, Al, Bh, Bl;
      Ah.u = *(const uint4*)&xsh[wr * 32 + l31][ac];
      Al.u = *(const uint4*)&xsl[wr * 32 + l31][ac];
      Bh.u = *(const uint4*)&wsh[wc * 32 + l31][ac];
      Bl.u = *(const uint4*)&wsl[wc * 32 + l31][ac];
      acc = __builtin_amdgcn_mfma_f32_32x32x16_bf16(Ah.s, Bh.s, acc, 0, 0, 0);
      acc = __builtin_amdgcn_mfma_f32_32x32x16_bf16(Al.s, Bh.s, acc, 0, 0, 0);
      acc = __builtin_amdgcn_mfma_f32_32x32x16_bf16(Ah.s, Bl.s, acc, 0, 0, 0);
    }
  }

  int o = colBase + wc * 32 + l31;
#pragma unroll
  for (int r = 0; r < 16; ++r) {
    int row = rowBase + wr * 32 + (r & 3) + 8 * (r >> 2) + 4 * lh;
    out[(size_t)row * EE + o] = acc[r];
  }
}

extern "C" void kernel_launch(void* const* d_in, const int* in_sizes, int n_in,
                              void* d_out, int out_size, void* d_ws, size_t ws_size,
                              hipStream_t stream) {
  const float* x   = (const float*)d_in[0];
  const float* Wq  = (const float*)d_in[1];
  const float* Wk  = (const float*)d_in[2];
  const float* Wv  = (const float*)d_in[3];
  const float* Wo  = (const float*)d_in[4];
  const float* rot = (const float*)d_in[5];
  float* ws  = (float*)d_ws;
  unsigned short* Qf  = (unsigned short*)(ws + OFF_QF);
  unsigned short* Kf  = (unsigned short*)(ws + OFF_KF);
  unsigned short* Vc  = (unsigned short*)(ws + OFF_VC);
  unsigned short* AOh = (unsigned short*)(ws + OFF_AOH);
  unsigned short* AOl = (unsigned short*)(ws + OFF_AOL);
  unsigned short* Wch = (unsigned short*)(ws + OFF_WCH);
  unsigned short* Wcl = (unsigned short*)(ws + OFF_WCL);
  unsigned short* Woh = (unsigned short*)(ws + OFF_WOH);
  unsigned short* Wol = (unsigned short*)(ws + OFF_WOL);
  float* out = (float*)d_out;

  fold_split_k<<<dim3((576 * EE + EE * EE) / 256), 256, 0, stream>>>(
      Wq, Wk, Wv, Wo, rot,
      (__hip_bfloat16*)Wch, (__hip_bfloat16*)Wcl,
      (__hip_bfloat16*)Woh, (__hip_bfloat16*)Wol);
  gemm_qkv_k<<<dim3(9, 64), 256, 0, stream>>>(x, Wch, Wcl,
                                              (__hip_bfloat16*)Qf, (__hip_bfloat16*)Kf,
                                              (__hip_bfloat16*)Vc);
  attn_k<<<dim3(BH * 8), 256, 0, stream>>>(Qf, Kf, Vc,
                                           (__hip_bfloat16*)AOh, (__hip_bfloat16*)AOl);
  gemm_out_k<<<dim3(3, 64), 256, 0, stream>>>(AOh, AOl, Woh, Wol, out);
}

// Round 14
// 64.388 us; speedup vs baseline: 1.0363x; 1.0334x over previous
//
#include <hip/hip_runtime.h>
#include <hip/hip_bf16.h>

// Problem dims
#define BB 4
#define SS 1024
#define EE 192
#define HH 64
// D = 3 (head dim)

constexpr int BH = BB * HH;  // 256

typedef __attribute__((ext_vector_type(8))) short bs8;    // 8 bf16 = 4 VGPR (MFMA A/B frag)
typedef __attribute__((ext_vector_type(16))) float fx16;  // MFMA C/D frag
union U4B { uint4 u; bs8 s; };

// ws layout (float units)
constexpr size_t OFF_QF  = 0;                             // (B*H,S,4) bf16: q0 q1 q2 0
constexpr size_t OFF_KF  = OFF_QF  + (size_t)BH*SS*2;     // (B*H,S,4) bf16: k0 k1 k2 0
constexpr size_t OFF_VC  = OFF_KF  + (size_t)BH*SS*2;     // (B*H,3,S) bf16 col-major
constexpr size_t OFF_AO  = OFF_VC  + (size_t)BH*SS*3/2;   // (B,S,E) fp32
constexpr size_t OFF_WCH = OFF_AO  + (size_t)BB*SS*EE;    // (576,192) bf16 hi (WqR|WkR|Wv)
constexpr size_t OFF_WCL = OFF_WCH + (size_t)576*EE/2;    // lo
constexpr size_t OFF_WOH = OFF_WCL + (size_t)576*EE/2;    // (192,192) bf16 hi (Wo)
constexpr size_t OFF_WOL = OFF_WOH + (size_t)EE*EE/2;     // lo

static __device__ __forceinline__ float fast_exp2(float x) {
#if __has_builtin(__builtin_amdgcn_exp2f)
  return __builtin_amdgcn_exp2f(x);
#else
  return exp2f(x);
#endif
}
static __device__ __forceinline__ float fast_rcp(float x) {
#if __has_builtin(__builtin_amdgcn_rcpf)
  return __builtin_amdgcn_rcpf(x);
#else
  return 1.0f / x;
#endif
}

// split a pair of fp32 into packed bf16 hi + bf16 lo (lo = residual)
static __device__ __forceinline__ void split2(float a, float b, unsigned& hi, unsigned& lo) {
  unsigned h;
  asm("v_cvt_pk_bf16_f32 %0, %1, %2" : "=v"(h) : "v"(a), "v"(b));
  float ha = __uint_as_float(h << 16);
  float hb = __uint_as_float(h & 0xFFFF0000u);
  float la = a - ha, lb = b - hb;
  unsigned l;
  asm("v_cvt_pk_bf16_f32 %0, %1, %2" : "=v"(l) : "v"(la), "v"(lb));
  hi = h; lo = l;
}

// Weight prep: fold per-head 3x3 rotation into Wq (with log2e/sqrt(3) scale)
// and Wk (fp32, exact), concat [WqR|WkR|Wv] as 576x192, split every matrix
// (incl. Wo) into bf16 hi + lo residual for split-bf16 MFMA GEMMs.
__global__ __launch_bounds__(256) void fold_split_k(
    const float* __restrict__ Wq, const float* __restrict__ Wk,
    const float* __restrict__ Wv, const float* __restrict__ Wo,
    const float* __restrict__ rot,
    __hip_bfloat16* __restrict__ Wch, __hip_bfloat16* __restrict__ Wcl,
    __hip_bfloat16* __restrict__ Woh, __hip_bfloat16* __restrict__ Wol)
{
  int t = blockIdx.x * 256 + threadIdx.x;
  float val;
  __hip_bfloat16 *ph, *pl;
  int idx;
  if (t < 576 * EE) {
    int o = t / EE, e = t - o * EE;
    int s3 = o / 192, oo = o - s3 * 192;
    int h = oo / 3, ep = oo - h * 3;
    if (s3 == 2) {
      val = Wv[(size_t)oo * EE + e];
    } else {
      const float* W = s3 ? Wk : Wq;
      float acc = 0.f;
#pragma unroll
      for (int d = 0; d < 3; ++d)
        acc += rot[h * 9 + d * 3 + ep] * W[(size_t)(h * 3 + d) * EE + e];
      val = acc * (s3 ? 1.0f : 0.8329876360019913f);  // log2(e)/sqrt(3) for Q
    }
    ph = Wch; pl = Wcl; idx = t;
  } else {
    int u = t - 576 * EE;
    if (u >= EE * EE) return;
    val = Wo[u]; ph = Woh; pl = Wol; idx = u;
  }
  __hip_bfloat16 hi = __float2bfloat16(val);
  float lo = val - __bfloat162float(hi);
  ph[idx] = hi;
  pl[idx] = __float2bfloat16(lo);
}

// QKV projection, split-bf16 MFMA: C(4096x576) = x(4096x192) @ Wcat^T.
// Block = 64x64 output tile, 4 waves (2x2 of 32x32), K chunked by 64.
// acc = Ah*Bh + Al*Bh + Ah*Bl (lo*lo dropped, ~2^-18) -> fp32-grade result.
// Q,K -> bf16 (B*H,S,4) slot3=0; V -> bf16 col-major (B*H,3,S).
__global__ __launch_bounds__(256) void gemm_qkv_k(
    const float* __restrict__ x,
    const unsigned short* __restrict__ Wch, const unsigned short* __restrict__ Wcl,
    __hip_bfloat16* __restrict__ Qf, __hip_bfloat16* __restrict__ Kf,
    __hip_bfloat16* __restrict__ Vc)
{
  __shared__ __align__(16) short xsh[64][72], xsl[64][72];
  __shared__ __align__(16) short wsh[64][72], wsl[64][72];
  int colBase = blockIdx.x * 64;   // col-group over 576 outs
  int rowBase = blockIdx.y * 64;   // row-group over 4096 rows
  int t = threadIdx.x;
  int lane = t & 63, w = t >> 6;
  int wr = w >> 1, wc = w & 1;
  int l31 = lane & 31, lh = lane >> 5;

  const fx16 zc = {0,0,0,0, 0,0,0,0, 0,0,0,0, 0,0,0,0};
  fx16 acc = zc;

  int srow = t >> 2, sk = (t & 3) * 16;

  for (int kk = 0; kk < 3; ++kk) {
    const float4* xg = (const float4*)&x[(size_t)(rowBase + srow) * EE + kk * 64 + sk];
    float4 v0 = xg[0], v1 = xg[1], v2 = xg[2], v3 = xg[3];
    const uint4* whg = (const uint4*)&Wch[(size_t)(colBase + srow) * EE + kk * 64 + sk];
    const uint4* wlg = (const uint4*)&Wcl[(size_t)(colBase + srow) * EE + kk * 64 + sk];
    uint4 wh0 = whg[0], wh1 = whg[1], wl0 = wlg[0], wl1 = wlg[1];

    unsigned hu[8], lu[8];
    split2(v0.x, v0.y, hu[0], lu[0]); split2(v0.z, v0.w, hu[1], lu[1]);
    split2(v1.x, v1.y, hu[2], lu[2]); split2(v1.z, v1.w, hu[3], lu[3]);
    split2(v2.x, v2.y, hu[4], lu[4]); split2(v2.z, v2.w, hu[5], lu[5]);
    split2(v3.x, v3.y, hu[6], lu[6]); split2(v3.z, v3.w, hu[7], lu[7]);

    __syncthreads();  // previous chunk's MFMA reads complete
    *(uint4*)&xsh[srow][sk]     = make_uint4(hu[0], hu[1], hu[2], hu[3]);
    *(uint4*)&xsh[srow][sk + 8] = make_uint4(hu[4], hu[5], hu[6], hu[7]);
    *(uint4*)&xsl[srow][sk]     = make_uint4(lu[0], lu[1], lu[2], lu[3]);
    *(uint4*)&xsl[srow][sk + 8] = make_uint4(lu[4], lu[5], lu[6], lu[7]);
    *(uint4*)&wsh[srow][sk]     = wh0;
    *(uint4*)&wsh[srow][sk + 8] = wh1;
    *(uint4*)&wsl[srow][sk]     = wl0;
    *(uint4*)&wsl[srow][sk + 8] = wl1;
    __syncthreads();

#pragma unroll
    for (int ks = 0; ks < 4; ++ks) {
      int ac = ks * 16 + lh * 8;
      U4B Ah, Al, Bh, Bl;
      Ah.u = *(const uint4*)&xsh[wr * 32 + l31][ac];
      Al.u = *(const uint4*)&xsl[wr * 32 + l31][ac];
      Bh.u = *(const uint4*)&wsh[wc * 32 + l31][ac];
      Bl.u = *(const uint4*)&wsl[wc * 32 + l31][ac];
      acc = __builtin_amdgcn_mfma_f32_32x32x16_bf16(Ah.s, Bh.s, acc, 0, 0, 0);
      acc = __builtin_amdgcn_mfma_f32_32x32x16_bf16(Al.s, Bh.s, acc, 0, 0, 0);
      acc = __builtin_amdgcn_mfma_f32_32x32x16_bf16(Ah.s, Bl.s, acc, 0, 0, 0);
    }
  }

  // epilogue: C/D layout col=l31, row=(r&3)+8*(r>>2)+4*lh
  int o = colBase + wc * 32 + l31;
  int s3 = o / 192, oo = o - s3 * 192;
  int hh = oo / 3, d = oo - hh * 3;
#pragma unroll
  for (int r = 0; r < 16; ++r) {
    int row = rowBase + wr * 32 + (r & 3) + 8 * (r >> 2) + 4 * lh;
    int b = row >> 10, s = row & (SS - 1);
    size_t bh = (size_t)(b * HH + hh);
    float v = acc[r];
    if (s3 == 0) {
      Qf[(bh * SS + s) * 4 + d] = __float2bfloat16(v);
      if (d == 2) Qf[(bh * SS + s) * 4 + 3] = __float2bfloat16(0.0f);
    } else if (s3 == 1) {
      Kf[(bh * SS + s) * 4 + d] = __float2bfloat16(v);
      if (d == 2) Kf[(bh * SS + s) * 4 + 3] = __float2bfloat16(0.0f);
    } else {
      Vc[bh * (3 * SS) + (size_t)d * SS + s] = __float2bfloat16(v);
    }
  }
}

// MFMA attention (r9-proven body, bf16 Q input). Block = (head, query-eighth):
// 2048 blocks. Swapped QK^T (A=K, B=Q) -> D[key][query]; B(=Q) zero for k>=3
// so K is (S,4) bf16, A-frag {k-pair,0,0}. exp2 in-register, cvt_pk +
// permlane32_swap -> PV A-frags; V ones-column yields l via the PV MFMA.
// Epilogue: single fp32 AO write (r13's producer-side hi/lo split doubled
// strided write traffic, +3us — consumer-side split in gemm_out is free).
// NOTE: exactly ONE S-tuple live at a time — dual-chain (r10/r11) corrupted S.
__global__ __launch_bounds__(256, 4) void attn_k(
    const unsigned short* __restrict__ Qfg, const unsigned short* __restrict__ Kfg,
    const unsigned short* __restrict__ Vcg, float* __restrict__ AO)
{
  __shared__ __align__(16) short KfL[1024 * 4];   // 8 KB: [key][k0 k1 k2 0]
  __shared__ __align__(16) short VcL[4 * 1040];   // 8.1 KB: rows v0 v1 v2 ones
  int bh = blockIdx.x & 255;       // eighth-major: same-head blocks 256 apart (same XCD)
  int eighth = blockIdx.x >> 8;
  int b = bh >> 6, h = bh & 63;

  const uint2* ksrc = (const uint2*)Kfg + (size_t)bh * 1024;
  uint2* kdst = (uint2*)KfL;
  for (int i = threadIdx.x; i < 1024; i += 256) kdst[i] = ksrc[i];
  const uint4* vsrc = (const uint4*)Vcg + (size_t)bh * 384;
  for (int i = threadIdx.x; i < 384; i += 256) {
    int r = i >> 7, cq = i & 127;
    *(uint4*)(VcL + r * 1040 + cq * 8) = vsrc[i];
  }
  {
    unsigned v1 = 0x3F803F80u;
    for (int i = threadIdx.x; i < 128; i += 256)
      *(uint4*)(VcL + 3 * 1040 + i * 8) = make_uint4(v1, v1, v1, v1);
  }
  __syncthreads();

  int lane = threadIdx.x & 63, w = threadIdx.x >> 6;
  int h32 = lane >> 5;
  int col = lane & 31;
  int q32 = eighth * 128 + w * 32;

  // Q B-frag: direct bf16 pair load (h1 lanes = zero half of K-dim)
  uint2 qq = *(const uint2*)(Qfg + ((size_t)bh * SS + q32 + col) * 4);
  U4B bq; bq.u = make_uint4(h32 ? 0u : qq.x, h32 ? 0u : qq.y, 0u, 0u);

  const fx16 zc = {0,0,0,0, 0,0,0,0, 0,0,0,0, 0,0,0,0};
  fx16 accPV = zc;
  int vbase = (col & 3) * 1040 + 8 * h32;

  for (int kt = 0; kt < 32; ++kt) {
    uint2 kk = *(const uint2*)(KfL + (size_t)(kt * 32 + col) * 4);
    U4B ak; ak.u = make_uint4(kk.x, kk.y, 0u, 0u);
    U4B bv1; bv1.u = *(const uint4*)(VcL + vbase + kt * 32);
    U4B bv2; bv2.u = *(const uint4*)(VcL + vbase + kt * 32 + 16);

    fx16 S = __builtin_amdgcn_mfma_f32_32x32x16_bf16(ak.s, bq.s, zc, 0, 0, 0);
    asm("" : "+v"(S));
#pragma unroll
    for (int i = 0; i < 16; ++i) S[i] = fast_exp2(S[i]);
    unsigned u0, u1, u2, u3, u4, u5, u6, u7;
    asm("v_cvt_pk_bf16_f32 %0, %1, %2" : "=v"(u0) : "v"(S[0]),  "v"(S[1]));
    asm("v_cvt_pk_bf16_f32 %0, %1, %2" : "=v"(u1) : "v"(S[2]),  "v"(S[3]));
    asm("v_cvt_pk_bf16_f32 %0, %1, %2" : "=v"(u2) : "v"(S[4]),  "v"(S[5]));
    asm("v_cvt_pk_bf16_f32 %0, %1, %2" : "=v"(u3) : "v"(S[6]),  "v"(S[7]));
    asm("v_cvt_pk_bf16_f32 %0, %1, %2" : "=v"(u4) : "v"(S[8]),  "v"(S[9]));
    asm("v_cvt_pk_bf16_f32 %0, %1, %2" : "=v"(u5) : "v"(S[10]), "v"(S[11]));
    asm("v_cvt_pk_bf16_f32 %0, %1, %2" : "=v"(u6) : "v"(S[12]), "v"(S[13]));
    asm("v_cvt_pk_bf16_f32 %0, %1, %2" : "=v"(u7) : "v"(S[14]), "v"(S[15]));
    asm("v_permlane32_swap_b32 %0, %1" : "+v"(u0), "+v"(u2));
    asm("v_permlane32_swap_b32 %0, %1" : "+v"(u1), "+v"(u3));
    asm("v_permlane32_swap_b32 %0, %1" : "+v"(u4), "+v"(u6));
    asm("v_permlane32_swap_b32 %0, %1" : "+v"(u5), "+v"(u7));
    U4B p1; p1.u = make_uint4(u0, u1, u2, u3);
    U4B p2; p2.u = make_uint4(u4, u5, u6, u7);
    accPV = __builtin_amdgcn_mfma_f32_32x32x16_bf16(p1.s, bv1.s, accPV, 0, 0, 0);
    accPV = __builtin_amdgcn_mfma_f32_32x32x16_bf16(p2.s, bv2.s, accPV, 0, 0, 0);
  }

  // Epilogue: D_pv[query row][col]: col 0-2 = o, col 3 = l. Normalize + write.
  int base3 = (lane & 32) | 3;
  float inv[16];
#pragma unroll
  for (int rg = 0; rg < 16; ++rg)
    inv[rg] = __shfl(fast_rcp(accPV[rg]), base3, 64);
  if (col < 3) {
#pragma unroll
    for (int rg = 0; rg < 16; ++rg) {
      int row = (rg & 3) + 8 * (rg >> 2) + 4 * h32;
      AO[((size_t)(b * SS + q32 + row)) * EE + h * 3 + col] = accPV[rg] * inv[rg];
    }
  }
}

// Output projection, split-bf16 MFMA: out(4096x192) = AO @ Wo^T. grid (3,64).
__global__ __launch_bounds__(256) void gemm_out_k(
    const float* __restrict__ AO,
    const unsigned short* __restrict__ Woh, const unsigned short* __restrict__ Wol,
    float* __restrict__ out)
{
  __shared__ __align__(16) short xsh[64][72], xsl[64][72];
  __shared__ __align__(16) short wsh[64][72], wsl[64][72];
  int colBase = blockIdx.x * 64;
  int rowBase = blockIdx.y * 64;
  int t = threadIdx.x;
  int lane = t & 63, w = t >> 6;
  int wr = w >> 1, wc = w & 1;
  int l31 = lane & 31, lh = lane >> 5;

  const fx16 zc = {0,0,0,0, 0,0,0,0, 0,0,0,0, 0,0,0,0};
  fx16 acc = zc;

  int srow = t >> 2, sk = (t & 3) * 16;

  for (int kk = 0; kk < 3; ++kk) {
    const float4* xg = (const float4*)&AO[(size_t)(rowBase + srow) * EE + kk * 64 + sk];
    float4 v0 = xg[0], v1 = xg[1], v2 = xg[2], v3 = xg[3];
    const uint4* whg = (const uint4*)&Woh[(size_t)(colBase + srow) * EE + kk * 64 + sk];
    const uint4* wlg = (const uint4*)&Wol[(size_t)(colBase + srow) * EE + kk * 64 + sk];
    uint4 wh0 = whg[0], wh1 = whg[1], wl0 = wlg[0], wl1 = wlg[1];

    unsigned hu[8], lu[8];
    split2(v0.x, v0.y, hu[0], lu[0]); split2(v0.z, v0.w, hu[1], lu[1]);
    split2(v1.x, v1.y, hu[2], lu[2]); split2(v1.z, v1.w, hu[3], lu[3]);
    split2(v2.x, v2.y, hu[4], lu[4]); split2(v2.z, v2.w, hu[5], lu[5]);
    split2(v3.x, v3.y, hu[6], lu[6]); split2(v3.z, v3.w, hu[7], lu[7]);

    __syncthreads();
    *(uint4*)&xsh[srow][sk]     = make_uint4(hu[0], hu[1], hu[2], hu[3]);
    *(uint4*)&xsh[srow][sk + 8] = make_uint4(hu[4], hu[5], hu[6], hu[7]);
    *(uint4*)&xsl[srow][sk]     = make_uint4(lu[0], lu[1], lu[2], lu[3]);
    *(uint4*)&xsl[srow][sk + 8] = make_uint4(lu[4], lu[5], lu[6], lu[7]);
    *(uint4*)&wsh[srow][sk]     = wh0;
    *(uint4*)&wsh[srow][sk + 8] = wh1;
    *(uint4*)&wsl[srow][sk]     = wl0;
    *(uint4*)&wsl[srow][sk + 8] = wl1;
    __syncthreads();

#pragma unroll
    for (int ks = 0; ks < 4; ++ks) {
      int ac = ks * 16 + lh * 8;
      U4B Ah, Al, Bh, Bl;
      Ah.u = *(const uint4*)&xsh[wr * 32 + l31][ac];
      Al.u = *(const uint4*)&xsl[wr * 32 + l31][ac];
      Bh.u = *(const uint4*)&wsh[wc * 32 + l31][ac];
      Bl.u = *(const uint4*)&wsl[wc * 32 + l31][ac];
      acc = __builtin_amdgcn_mfma_f32_32x32x16_bf16(Ah.s, Bh.s, acc, 0, 0, 0);
      acc = __builtin_amdgcn_mfma_f32_32x32x16_bf16(Al.s, Bh.s, acc, 0, 0, 0);
      acc = __builtin_amdgcn_mfma_f32_32x32x16_bf16(Ah.s, Bl.s, acc, 0, 0, 0);
    }
  }

  int o = colBase + wc * 32 + l31;
#pragma unroll
  for (int r = 0; r < 16; ++r) {
    int row = rowBase + wr * 32 + (r & 3) + 8 * (r >> 2) + 4 * lh;
    out[(size_t)row * EE + o] = acc[r];
  }
}

extern "C" void kernel_launch(void* const* d_in, const int* in_sizes, int n_in,
                              void* d_out, int out_size, void* d_ws, size_t ws_size,
                              hipStream_t stream) {
  const float* x   = (const float*)d_in[0];
  const float* Wq  = (const float*)d_in[1];
  const float* Wk  = (const float*)d_in[2];
  const float* Wv  = (const float*)d_in[3];
  const float* Wo  = (const float*)d_in[4];
  const float* rot = (const float*)d_in[5];
  float* ws  = (float*)d_ws;
  unsigned short* Qf  = (unsigned short*)(ws + OFF_QF);
  unsigned short* Kf  = (unsigned short*)(ws + OFF_KF);
  unsigned short* Vc  = (unsigned short*)(ws + OFF_VC);
  float* AO  = ws + OFF_AO;
  unsigned short* Wch = (unsigned short*)(ws + OFF_WCH);
  unsigned short* Wcl = (unsigned short*)(ws + OFF_WCL);
  unsigned short* Woh = (unsigned short*)(ws + OFF_WOH);
  unsigned short* Wol = (unsigned short*)(ws + OFF_WOL);
  float* out = (float*)d_out;

  fold_split_k<<<dim3((576 * EE + EE * EE) / 256), 256, 0, stream>>>(
      Wq, Wk, Wv, Wo, rot,
      (__hip_bfloat16*)Wch, (__hip_bfloat16*)Wcl,
      (__hip_bfloat16*)Woh, (__hip_bfloat16*)Wol);
  gemm_qkv_k<<<dim3(9, 64), 256, 0, stream>>>(x, Wch, Wcl,
                                              (__hip_bfloat16*)Qf, (__hip_bfloat16*)Kf,
                                              (__hip_bfloat16*)Vc);
  attn_k<<<dim3(BH * 8), 256, 0, stream>>>(Qf, Kf, Vc, AO);
  gemm_out_k<<<dim3(3, 64), 256, 0, stream>>>(AO, Woh, Wol, out);
}

// Round 15
// 64.349 us; speedup vs baseline: 1.0369x; 1.0006x over previous
//
#include <hip/hip_runtime.h>
#include <hip/hip_bf16.h>

// Problem dims
#define BB 4
#define SS 1024
#define EE 192
#define HH 64
// D = 3 (head dim)

constexpr int BH = BB * HH;  // 256

typedef __attribute__((ext_vector_type(8))) short bs8;    // 8 bf16 = 4 VGPR (MFMA A/B frag)
typedef __attribute__((ext_vector_type(16))) float fx16;  // MFMA C/D frag
union U4B { uint4 u; bs8 s; };

// ws layout (float units)
constexpr size_t OFF_QF  = 0;                             // (B*H,S,4) bf16: q0 q1 q2 0
constexpr size_t OFF_KF  = OFF_QF  + (size_t)BH*SS*2;     // (B*H,S,4) bf16: k0 k1 k2 0
constexpr size_t OFF_VC  = OFF_KF  + (size_t)BH*SS*2;     // (B*H,3,S) bf16 col-major
constexpr size_t OFF_AO  = OFF_VC  + (size_t)BH*SS*3/2;   // (B,S,E) fp32
constexpr size_t OFF_WCH = OFF_AO  + (size_t)BB*SS*EE;    // (576,192) bf16 hi (WqR|WkR|Wv)
constexpr size_t OFF_WCL = OFF_WCH + (size_t)576*EE/2;    // lo
constexpr size_t OFF_WOH = OFF_WCL + (size_t)576*EE/2;    // (192,192) bf16 hi (Wo)
constexpr size_t OFF_WOL = OFF_WOH + (size_t)EE*EE/2;     // lo

static __device__ __forceinline__ float fast_exp2(float x) {
#if __has_builtin(__builtin_amdgcn_exp2f)
  return __builtin_amdgcn_exp2f(x);
#else
  return exp2f(x);
#endif
}
static __device__ __forceinline__ float fast_rcp(float x) {
#if __has_builtin(__builtin_amdgcn_rcpf)
  return __builtin_amdgcn_rcpf(x);
#else
  return 1.0f / x;
#endif
}

// split a pair of fp32 into packed bf16 hi + bf16 lo (lo = residual)
static __device__ __forceinline__ void split2(float a, float b, unsigned& hi, unsigned& lo) {
  unsigned h;
  asm("v_cvt_pk_bf16_f32 %0, %1, %2" : "=v"(h) : "v"(a), "v"(b));
  float ha = __uint_as_float(h << 16);
  float hb = __uint_as_float(h & 0xFFFF0000u);
  float la = a - ha, lb = b - hb;
  unsigned l;
  asm("v_cvt_pk_bf16_f32 %0, %1, %2" : "=v"(l) : "v"(la), "v"(lb));
  hi = h; lo = l;
}

// Weight prep: fold per-head 3x3 rotation into Wq (with log2e/sqrt(3) scale)
// and Wk (fp32, exact), concat [WqR|WkR|Wv] as 576x192, split every matrix
// (incl. Wo) into bf16 hi + lo residual for split-bf16 MFMA GEMMs.
__global__ __launch_bounds__(256) void fold_split_k(
    const float* __restrict__ Wq, const float* __restrict__ Wk,
    const float* __restrict__ Wv, const float* __restrict__ Wo,
    const float* __restrict__ rot,
    __hip_bfloat16* __restrict__ Wch, __hip_bfloat16* __restrict__ Wcl,
    __hip_bfloat16* __restrict__ Woh, __hip_bfloat16* __restrict__ Wol)
{
  int t = blockIdx.x * 256 + threadIdx.x;
  float val;
  __hip_bfloat16 *ph, *pl;
  int idx;
  if (t < 576 * EE) {
    int o = t / EE, e = t - o * EE;
    int s3 = o / 192, oo = o - s3 * 192;
    int h = oo / 3, ep = oo - h * 3;
    if (s3 == 2) {
      val = Wv[(size_t)oo * EE + e];
    } else {
      const float* W = s3 ? Wk : Wq;
      float acc = 0.f;
#pragma unroll
      for (int d = 0; d < 3; ++d)
        acc += rot[h * 9 + d * 3 + ep] * W[(size_t)(h * 3 + d) * EE + e];
      val = acc * (s3 ? 1.0f : 0.8329876360019913f);  // log2(e)/sqrt(3) for Q
    }
    ph = Wch; pl = Wcl; idx = t;
  } else {
    int u = t - 576 * EE;
    if (u >= EE * EE) return;
    val = Wo[u]; ph = Woh; pl = Wol; idx = u;
  }
  __hip_bfloat16 hi = __float2bfloat16(val);
  float lo = val - __bfloat162float(hi);
  ph[idx] = hi;
  pl[idx] = __float2bfloat16(lo);
}

// QKV projection, split-bf16 MFMA: C(4096x576) = x(4096x192) @ Wcat^T.
// Block = 64x64 output tile, 4 waves (2x2 of 32x32), K chunked by 64.
// acc = Ah*Bh + Al*Bh + Ah*Bl (lo*lo dropped, ~2^-18) -> fp32-grade result.
// Q,K -> bf16 (B*H,S,4) slot3=0; V -> bf16 col-major (B*H,3,S).
__global__ __launch_bounds__(256) void gemm_qkv_k(
    const float* __restrict__ x,
    const unsigned short* __restrict__ Wch, const unsigned short* __restrict__ Wcl,
    __hip_bfloat16* __restrict__ Qf, __hip_bfloat16* __restrict__ Kf,
    __hip_bfloat16* __restrict__ Vc)
{
  __shared__ __align__(16) short xsh[64][72], xsl[64][72];
  __shared__ __align__(16) short wsh[64][72], wsl[64][72];
  int colBase = blockIdx.x * 64;   // col-group over 576 outs
  int rowBase = blockIdx.y * 64;   // row-group over 4096 rows
  int t = threadIdx.x;
  int lane = t & 63, w = t >> 6;
  int wr = w >> 1, wc = w & 1;
  int l31 = lane & 31, lh = lane >> 5;

  const fx16 zc = {0,0,0,0, 0,0,0,0, 0,0,0,0, 0,0,0,0};
  fx16 acc = zc;

  int srow = t >> 2, sk = (t & 3) * 16;

  for (int kk = 0; kk < 3; ++kk) {
    const float4* xg = (const float4*)&x[(size_t)(rowBase + srow) * EE + kk * 64 + sk];
    float4 v0 = xg[0], v1 = xg[1], v2 = xg[2], v3 = xg[3];
    const uint4* whg = (const uint4*)&Wch[(size_t)(colBase + srow) * EE + kk * 64 + sk];
    const uint4* wlg = (const uint4*)&Wcl[(size_t)(colBase + srow) * EE + kk * 64 + sk];
    uint4 wh0 = whg[0], wh1 = whg[1], wl0 = wlg[0], wl1 = wlg[1];

    unsigned hu[8], lu[8];
    split2(v0.x, v0.y, hu[0], lu[0]); split2(v0.z, v0.w, hu[1], lu[1]);
    split2(v1.x, v1.y, hu[2], lu[2]); split2(v1.z, v1.w, hu[3], lu[3]);
    split2(v2.x, v2.y, hu[4], lu[4]); split2(v2.z, v2.w, hu[5], lu[5]);
    split2(v3.x, v3.y, hu[6], lu[6]); split2(v3.z, v3.w, hu[7], lu[7]);

    __syncthreads();  // previous chunk's MFMA reads complete
    *(uint4*)&xsh[srow][sk]     = make_uint4(hu[0], hu[1], hu[2], hu[3]);
    *(uint4*)&xsh[srow][sk + 8] = make_uint4(hu[4], hu[5], hu[6], hu[7]);
    *(uint4*)&xsl[srow][sk]     = make_uint4(lu[0], lu[1], lu[2], lu[3]);
    *(uint4*)&xsl[srow][sk + 8] = make_uint4(lu[4], lu[5], lu[6], lu[7]);
    *(uint4*)&wsh[srow][sk]     = wh0;
    *(uint4*)&wsh[srow][sk + 8] = wh1;
    *(uint4*)&wsl[srow][sk]     = wl0;
    *(uint4*)&wsl[srow][sk + 8] = wl1;
    __syncthreads();

#pragma unroll
    for (int ks = 0; ks < 4; ++ks) {
      int ac = ks * 16 + lh * 8;
      U4B Ah, Al, Bh, Bl;
      Ah.u = *(const uint4*)&xsh[wr * 32 + l31][ac];
      Al.u = *(const uint4*)&xsl[wr * 32 + l31][ac];
      Bh.u = *(const uint4*)&wsh[wc * 32 + l31][ac];
      Bl.u = *(const uint4*)&wsl[wc * 32 + l31][ac];
      acc = __builtin_amdgcn_mfma_f32_32x32x16_bf16(Ah.s, Bh.s, acc, 0, 0, 0);
      acc = __builtin_amdgcn_mfma_f32_32x32x16_bf16(Al.s, Bh.s, acc, 0, 0, 0);
      acc = __builtin_amdgcn_mfma_f32_32x32x16_bf16(Ah.s, Bl.s, acc, 0, 0, 0);
    }
  }

  // epilogue: C/D layout col=l31, row=(r&3)+8*(r>>2)+4*lh
  int o = colBase + wc * 32 + l31;
  int s3 = o / 192, oo = o - s3 * 192;
  int hh = oo / 3, d = oo - hh * 3;
#pragma unroll
  for (int r = 0; r < 16; ++r) {
    int row = rowBase + wr * 32 + (r & 3) + 8 * (r >> 2) + 4 * lh;
    int b = row >> 10, s = row & (SS - 1);
    size_t bh = (size_t)(b * HH + hh);
    float v = acc[r];
    if (s3 == 0) {
      Qf[(bh * SS + s) * 4 + d] = __float2bfloat16(v);
      if (d == 2) Qf[(bh * SS + s) * 4 + 3] = __float2bfloat16(0.0f);
    } else if (s3 == 1) {
      Kf[(bh * SS + s) * 4 + d] = __float2bfloat16(v);
      if (d == 2) Kf[(bh * SS + s) * 4 + 3] = __float2bfloat16(0.0f);
    } else {
      Vc[bh * (3 * SS) + (size_t)d * SS + s] = __float2bfloat16(v);
    }
  }
}

// MFMA attention (r14 body; kt loop unrolled x2 so the COMPILER can
// software-pipeline adjacent independent iterations — unlike r10/r11's
// manual dual-chain, hazard/regalloc choices stay fully compiler-owned.
// Empty-asm pin on S removed (perf-neutral per r8, and it's a scheduling
// barrier). Block = (head, query-eighth): 2048 blocks. Swapped QK^T
// (A=K, B=Q) -> D[key][query]; B(=Q) zero for k>=3 so K is (S,4) bf16,
// A-frag {k-pair,0,0}. exp2 in-register, cvt_pk + permlane32_swap ->
// PV A-frags; V ones-column yields l via the PV MFMA.
__global__ __launch_bounds__(256, 4) void attn_k(
    const unsigned short* __restrict__ Qfg, const unsigned short* __restrict__ Kfg,
    const unsigned short* __restrict__ Vcg, float* __restrict__ AO)
{
  __shared__ __align__(16) short KfL[1024 * 4];   // 8 KB: [key][k0 k1 k2 0]
  __shared__ __align__(16) short VcL[4 * 1040];   // 8.1 KB: rows v0 v1 v2 ones
  int bh = blockIdx.x & 255;       // eighth-major: same-head blocks 256 apart (same XCD)
  int eighth = blockIdx.x >> 8;
  int b = bh >> 6, h = bh & 63;

  const uint2* ksrc = (const uint2*)Kfg + (size_t)bh * 1024;
  uint2* kdst = (uint2*)KfL;
  for (int i = threadIdx.x; i < 1024; i += 256) kdst[i] = ksrc[i];
  const uint4* vsrc = (const uint4*)Vcg + (size_t)bh * 384;
  for (int i = threadIdx.x; i < 384; i += 256) {
    int r = i >> 7, cq = i & 127;
    *(uint4*)(VcL + r * 1040 + cq * 8) = vsrc[i];
  }
  {
    unsigned v1 = 0x3F803F80u;
    for (int i = threadIdx.x; i < 128; i += 256)
      *(uint4*)(VcL + 3 * 1040 + i * 8) = make_uint4(v1, v1, v1, v1);
  }
  __syncthreads();

  int lane = threadIdx.x & 63, w = threadIdx.x >> 6;
  int h32 = lane >> 5;
  int col = lane & 31;
  int q32 = eighth * 128 + w * 32;

  // Q B-frag: direct bf16 pair load (h1 lanes = zero half of K-dim)
  uint2 qq = *(const uint2*)(Qfg + ((size_t)bh * SS + q32 + col) * 4);
  U4B bq; bq.u = make_uint4(h32 ? 0u : qq.x, h32 ? 0u : qq.y, 0u, 0u);

  const fx16 zc = {0,0,0,0, 0,0,0,0, 0,0,0,0, 0,0,0,0};
  fx16 accPV = zc;
  int vbase = (col & 3) * 1040 + 8 * h32;

#pragma unroll 2
  for (int kt = 0; kt < 32; ++kt) {
    uint2 kk = *(const uint2*)(KfL + (size_t)(kt * 32 + col) * 4);
    U4B ak; ak.u = make_uint4(kk.x, kk.y, 0u, 0u);
    U4B bv1; bv1.u = *(const uint4*)(VcL + vbase + kt * 32);
    U4B bv2; bv2.u = *(const uint4*)(VcL + vbase + kt * 32 + 16);

    fx16 S = __builtin_amdgcn_mfma_f32_32x32x16_bf16(ak.s, bq.s, zc, 0, 0, 0);
#pragma unroll
    for (int i = 0; i < 16; ++i) S[i] = fast_exp2(S[i]);
    unsigned u0, u1, u2, u3, u4, u5, u6, u7;
    asm("v_cvt_pk_bf16_f32 %0, %1, %2" : "=v"(u0) : "v"(S[0]),  "v"(S[1]));
    asm("v_cvt_pk_bf16_f32 %0, %1, %2" : "=v"(u1) : "v"(S[2]),  "v"(S[3]));
    asm("v_cvt_pk_bf16_f32 %0, %1, %2" : "=v"(u2) : "v"(S[4]),  "v"(S[5]));
    asm("v_cvt_pk_bf16_f32 %0, %1, %2" : "=v"(u3) : "v"(S[6]),  "v"(S[7]));
    asm("v_cvt_pk_bf16_f32 %0, %1, %2" : "=v"(u4) : "v"(S[8]),  "v"(S[9]));
    asm("v_cvt_pk_bf16_f32 %0, %1, %2" : "=v"(u5) : "v"(S[10]), "v"(S[11]));
    asm("v_cvt_pk_bf16_f32 %0, %1, %2" : "=v"(u6) : "v"(S[12]), "v"(S[13]));
    asm("v_cvt_pk_bf16_f32 %0, %1, %2" : "=v"(u7) : "v"(S[14]), "v"(S[15]));
    asm("v_permlane32_swap_b32 %0, %1" : "+v"(u0), "+v"(u2));
    asm("v_permlane32_swap_b32 %0, %1" : "+v"(u1), "+v"(u3));
    asm("v_permlane32_swap_b32 %0, %1" : "+v"(u4), "+v"(u6));
    asm("v_permlane32_swap_b32 %0, %1" : "+v"(u5), "+v"(u7));
    U4B p1; p1.u = make_uint4(u0, u1, u2, u3);
    U4B p2; p2.u = make_uint4(u4, u5, u6, u7);
    accPV = __builtin_amdgcn_mfma_f32_32x32x16_bf16(p1.s, bv1.s, accPV, 0, 0, 0);
    accPV = __builtin_amdgcn_mfma_f32_32x32x16_bf16(p2.s, bv2.s, accPV, 0, 0, 0);
  }

  // Epilogue: D_pv[query row][col]: col 0-2 = o, col 3 = l. Normalize + write.
  int base3 = (lane & 32) | 3;
  float inv[16];
#pragma unroll
  for (int rg = 0; rg < 16; ++rg)
    inv[rg] = __shfl(fast_rcp(accPV[rg]), base3, 64);
  if (col < 3) {
#pragma unroll
    for (int rg = 0; rg < 16; ++rg) {
      int row = (rg & 3) + 8 * (rg >> 2) + 4 * h32;
      AO[((size_t)(b * SS + q32 + row)) * EE + h * 3 + col] = accPV[rg] * inv[rg];
    }
  }
}

// Output projection, split-bf16 MFMA: out(4096x192) = AO @ Wo^T. grid (3,64).
__global__ __launch_bounds__(256) void gemm_out_k(
    const float* __restrict__ AO,
    const unsigned short* __restrict__ Woh, const unsigned short* __restrict__ Wol,
    float* __restrict__ out)
{
  __shared__ __align__(16) short xsh[64][72], xsl[64][72];
  __shared__ __align__(16) short wsh[64][72], wsl[64][72];
  int colBase = blockIdx.x * 64;
  int rowBase = blockIdx.y * 64;
  int t = threadIdx.x;
  int lane = t & 63, w = t >> 6;
  int wr = w >> 1, wc = w & 1;
  int l31 = lane & 31, lh = lane >> 5;

  const fx16 zc = {0,0,0,0, 0,0,0,0, 0,0,0,0, 0,0,0,0};
  fx16 acc = zc;

  int srow = t >> 2, sk = (t & 3) * 16;

  for (int kk = 0; kk < 3; ++kk) {
    const float4* xg = (const float4*)&AO[(size_t)(rowBase + srow) * EE + kk * 64 + sk];
    float4 v0 = xg[0], v1 = xg[1], v2 = xg[2], v3 = xg[3];
    const uint4* whg = (const uint4*)&Woh[(size_t)(colBase + srow) * EE + kk * 64 + sk];
    const uint4* wlg = (const uint4*)&Wol[(size_t)(colBase + srow) * EE + kk * 64 + sk];
    uint4 wh0 = whg[0], wh1 = whg[1], wl0 = wlg[0], wl1 = wlg[1];

    unsigned hu[8], lu[8];
    split2(v0.x, v0.y, hu[0], lu[0]); split2(v0.z, v0.w, hu[1], lu[1]);
    split2(v1.x, v1.y, hu[2], lu[2]); split2(v1.z, v1.w, hu[3], lu[3]);
    split2(v2.x, v2.y, hu[4], lu[4]); split2(v2.z, v2.w, hu[5], lu[5]);
    split2(v3.x, v3.y, hu[6], lu[6]); split2(v3.z, v3.w, hu[7], lu[7]);

    __syncthreads();
    *(uint4*)&xsh[srow][sk]     = make_uint4(hu[0], hu[1], hu[2], hu[3]);
    *(uint4*)&xsh[srow][sk + 8] = make_uint4(hu[4], hu[5], hu[6], hu[7]);
    *(uint4*)&xsl[srow][sk]     = make_uint4(lu[0], lu[1], lu[2], lu[3]);
    *(uint4*)&xsl[srow][sk + 8] = make_uint4(lu[4], lu[5], lu[6], lu[7]);
    *(uint4*)&wsh[srow][sk]     = wh0;
    *(uint4*)&wsh[srow][sk + 8] = wh1;
    *(uint4*)&wsl[srow][sk]     = wl0;
    *(uint4*)&wsl[srow][sk + 8] = wl1;
    __syncthreads();

#pragma unroll
    for (int ks = 0; ks < 4; ++ks) {
      int ac = ks * 16 + lh * 8;
      U4B Ah, Al, Bh, Bl;
      Ah.u = *(const uint4*)&xsh[wr * 32 + l31][ac];
      Al.u = *(const uint4*)&xsl[wr * 32 + l31][ac];
      Bh.u = *(const uint4*)&wsh[wc * 32 + l31][ac];
      Bl.u = *(const uint4*)&wsl[wc * 32 + l31][ac];
      acc = __builtin_amdgcn_mfma_f32_32x32x16_bf16(Ah.s, Bh.s, acc, 0, 0, 0);
      acc = __builtin_amdgcn_mfma_f32_32x32x16_bf16(Al.s, Bh.s, acc, 0, 0, 0);
      acc = __builtin_amdgcn_mfma_f32_32x32x16_bf16(Ah.s, Bl.s, acc, 0, 0, 0);
    }
  }

  int o = colBase + wc * 32 + l31;
#pragma unroll
  for (int r = 0; r < 16; ++r) {
    int row = rowBase + wr * 32 + (r & 3) + 8 * (r >> 2) + 4 * lh;
    out[(size_t)row * EE + o] = acc[r];
  }
}

extern "C" void kernel_launch(void* const* d_in, const int* in_sizes, int n_in,
                              void* d_out, int out_size, void* d_ws, size_t ws_size,
                              hipStream_t stream) {
  const float* x   = (const float*)d_in[0];
  const float* Wq  = (const float*)d_in[1];
  const float* Wk  = (const float*)d_in[2];
  const float* Wv  = (const float*)d_in[3];
  const float* Wo  = (const float*)d_in[4];
  const float* rot = (const float*)d_in[5];
  float* ws  = (float*)d_ws;
  unsigned short* Qf  = (unsigned short*)(ws + OFF_QF);
  unsigned short* Kf  = (unsigned short*)(ws + OFF_KF);
  unsigned short* Vc  = (unsigned short*)(ws + OFF_VC);
  float* AO  = ws + OFF_AO;
  unsigned short* Wch = (unsigned short*)(ws + OFF_WCH);
  unsigned short* Wcl = (unsigned short*)(ws + OFF_WCL);
  unsigned short* Woh = (unsigned short*)(ws + OFF_WOH);
  unsigned short* Wol = (unsigned short*)(ws + OFF_WOL);
  float* out = (float*)d_out;

  fold_split_k<<<dim3((576 * EE + EE * EE) / 256), 256, 0, stream>>>(
      Wq, Wk, Wv, Wo, rot,
      (__hip_bfloat16*)Wch, (__hip_bfloat16*)Wcl,
      (__hip_bfloat16*)Woh, (__hip_bfloat16*)Wol);
  gemm_qkv_k<<<dim3(9, 64), 256, 0, stream>>>(x, Wch, Wcl,
                                              (__hip_bfloat16*)Qf, (__hip_bfloat16*)Kf,
                                              (__hip_bfloat16*)Vc);
  attn_k<<<dim3(BH * 8), 256, 0, stream>>>(Qf, Kf, Vc, AO);
  gemm_out_k<<<dim3(3, 64), 256, 0, stream>>>(AO, Woh, Wol, out);
}

// Round 16
// 63.749 us; speedup vs baseline: 1.0467x; 1.0094x over previous
//
#include <hip/hip_runtime.h>
#include <hip/hip_bf16.h>

// Problem dims
#define BB 4
#define SS 1024
#define EE 192
#define HH 64
// D = 3 (head dim)

constexpr int BH = BB * HH;  // 256

typedef __attribute__((ext_vector_type(8))) short bs8;    // 8 bf16 = 4 VGPR (MFMA A/B frag)
typedef __attribute__((ext_vector_type(16))) float fx16;  // MFMA C/D frag
union U4B { uint4 u; bs8 s; };

// ws layout (float units)
constexpr size_t OFF_QF  = 0;                             // (B*H,S,4) bf16: q0 q1 q2 0
constexpr size_t OFF_KF  = OFF_QF  + (size_t)BH*SS*2;     // (B*H,S,4) bf16: k0 k1 k2 0
constexpr size_t OFF_VC  = OFF_KF  + (size_t)BH*SS*2;     // (B*H,3,S) bf16 col-major
constexpr size_t OFF_AO  = OFF_VC  + (size_t)BH*SS*3/2;   // (B,S,E) fp32

static __device__ __forceinline__ float fast_exp2(float x) {
#if __has_builtin(__builtin_amdgcn_exp2f)
  return __builtin_amdgcn_exp2f(x);
#else
  return exp2f(x);
#endif
}
static __device__ __forceinline__ float fast_rcp(float x) {
#if __has_builtin(__builtin_amdgcn_rcpf)
  return __builtin_amdgcn_rcpf(x);
#else
  return 1.0f / x;
#endif
}

// split a pair of fp32 into packed bf16 hi + bf16 lo (lo = residual)
static __device__ __forceinline__ void split2(float a, float b, unsigned& hi, unsigned& lo) {
  unsigned h;
  asm("v_cvt_pk_bf16_f32 %0, %1, %2" : "=v"(h) : "v"(a), "v"(b));
  float ha = __uint_as_float(h << 16);
  float hb = __uint_as_float(h & 0xFFFF0000u);
  float la = a - ha, lb = b - hb;
  unsigned l;
  asm("v_cvt_pk_bf16_f32 %0, %1, %2" : "=v"(l) : "v"(la), "v"(lb));
  hi = h; lo = l;
}

// QKV projection, split-bf16 MFMA, with the per-head 3x3 rotation folded
// into the W staging ON THE FLY (replaces the former fold_split_k kernel):
// block col-group s3 = bx/3 is uniform (0->Q,1->K,2->V); Q/K blocks compute
// w = (rot fma-chain) * scale with the exact fp32 op order the old fold
// kernel used, then hi/lo-split into LDS. C(4096x576) = x @ Wcat^T.
// Block = 64x64 output tile, 4 waves (2x2 of 32x32), K chunked by 64.
// acc = Ah*Bh + Al*Bh + Ah*Bl (lo*lo dropped, ~2^-18) -> fp32-grade result.
// Q,K -> bf16 (B*H,S,4) slot3=0; V -> bf16 col-major (B*H,3,S).
__global__ __launch_bounds__(256) void gemm_qkv_k(
    const float* __restrict__ x,
    const float* __restrict__ Wq, const float* __restrict__ Wk,
    const float* __restrict__ Wv, const float* __restrict__ rot,
    __hip_bfloat16* __restrict__ Qf, __hip_bfloat16* __restrict__ Kf,
    __hip_bfloat16* __restrict__ Vc)
{
  __shared__ __align__(16) short xsh[64][72], xsl[64][72];
  __shared__ __align__(16) short wsh[64][72], wsl[64][72];
  int bx = blockIdx.x;             // 0..8
  int colBase = bx * 64;           // col-group over 576 outs
  int rowBase = blockIdx.y * 64;   // row-group over 4096 rows
  int t = threadIdx.x;
  int lane = t & 63, w = t >> 6;
  int wr = w >> 1, wc = w & 1;
  int l31 = lane & 31, lh = lane >> 5;
  int s3 = bx / 3;                 // uniform per block

  const fx16 zc = {0,0,0,0, 0,0,0,0, 0,0,0,0, 0,0,0,0};
  fx16 acc = zc;

  int srow = t >> 2, sk = (t & 3) * 16;

  // per-thread-uniform row params for the W side
  int o = colBase + srow;          // 0..575
  int oo = o - s3 * 192;
  int hh2 = oo / 3, ep = oo - hh2 * 3;
  const float *w0p, *w1p = nullptr, *w2p = nullptr;
  float rr0 = 0.f, rr1 = 0.f, rr2 = 0.f, wscale = 1.0f;
  if (s3 < 2) {
    const float* W = s3 ? Wk : Wq;
    wscale = s3 ? 1.0f : 0.8329876360019913f;   // log2(e)/sqrt(3) for Q
    rr0 = rot[hh2 * 9 + 0 + ep];
    rr1 = rot[hh2 * 9 + 3 + ep];
    rr2 = rot[hh2 * 9 + 6 + ep];
    w0p = W + (size_t)(hh2 * 3 + 0) * EE;
    w1p = W + (size_t)(hh2 * 3 + 1) * EE;
    w2p = W + (size_t)(hh2 * 3 + 2) * EE;
  } else {
    w0p = Wv + (size_t)oo * EE;
  }

  for (int kk = 0; kk < 3; ++kk) {
    int off = kk * 64 + sk;
    const float4* xg = (const float4*)&x[(size_t)(rowBase + srow) * EE + off];
    float4 v0 = xg[0], v1 = xg[1], v2 = xg[2], v3 = xg[3];

    // W side: fold + split on the fly
    unsigned whu[8], wlu[8];
    if (s3 < 2) {
      const float4* a4 = (const float4*)(w0p + off);
      const float4* b4 = (const float4*)(w1p + off);
      const float4* c4 = (const float4*)(w2p + off);
#pragma unroll
      for (int i = 0; i < 4; ++i) {
        float4 a = a4[i], bb = b4[i], c = c4[i];
        float f0 = fmaf(rr2, c.x, fmaf(rr1, bb.x, rr0 * a.x)) * wscale;
        float f1 = fmaf(rr2, c.y, fmaf(rr1, bb.y, rr0 * a.y)) * wscale;
        float f2 = fmaf(rr2, c.z, fmaf(rr1, bb.z, rr0 * a.z)) * wscale;
        float f3 = fmaf(rr2, c.w, fmaf(rr1, bb.w, rr0 * a.w)) * wscale;
        split2(f0, f1, whu[2 * i], wlu[2 * i]);
        split2(f2, f3, whu[2 * i + 1], wlu[2 * i + 1]);
      }
    } else {
      const float4* a4 = (const float4*)(w0p + off);
#pragma unroll
      for (int i = 0; i < 4; ++i) {
        float4 a = a4[i];
        split2(a.x, a.y, whu[2 * i], wlu[2 * i]);
        split2(a.z, a.w, whu[2 * i + 1], wlu[2 * i + 1]);
      }
    }

    unsigned hu[8], lu[8];
    split2(v0.x, v0.y, hu[0], lu[0]); split2(v0.z, v0.w, hu[1], lu[1]);
    split2(v1.x, v1.y, hu[2], lu[2]); split2(v1.z, v1.w, hu[3], lu[3]);
    split2(v2.x, v2.y, hu[4], lu[4]); split2(v2.z, v2.w, hu[5], lu[5]);
    split2(v3.x, v3.y, hu[6], lu[6]); split2(v3.z, v3.w, hu[7], lu[7]);

    __syncthreads();  // previous chunk's MFMA reads complete
    *(uint4*)&xsh[srow][sk]     = make_uint4(hu[0], hu[1], hu[2], hu[3]);
    *(uint4*)&xsh[srow][sk + 8] = make_uint4(hu[4], hu[5], hu[6], hu[7]);
    *(uint4*)&xsl[srow][sk]     = make_uint4(lu[0], lu[1], lu[2], lu[3]);
    *(uint4*)&xsl[srow][sk + 8] = make_uint4(lu[4], lu[5], lu[6], lu[7]);
    *(uint4*)&wsh[srow][sk]     = make_uint4(whu[0], whu[1], whu[2], whu[3]);
    *(uint4*)&wsh[srow][sk + 8] = make_uint4(whu[4], whu[5], whu[6], whu[7]);
    *(uint4*)&wsl[srow][sk]     = make_uint4(wlu[0], wlu[1], wlu[2], wlu[3]);
    *(uint4*)&wsl[srow][sk + 8] = make_uint4(wlu[4], wlu[5], wlu[6], wlu[7]);
    __syncthreads();

#pragma unroll
    for (int ks = 0; ks < 4; ++ks) {
      int ac = ks * 16 + lh * 8;
      U4B Ah, Al, Bh, Bl;
      Ah.u = *(const uint4*)&xsh[wr * 32 + l31][ac];
      Al.u = *(const uint4*)&xsl[wr * 32 + l31][ac];
      Bh.u = *(const uint4*)&wsh[wc * 32 + l31][ac];
      Bl.u = *(const uint4*)&wsl[wc * 32 + l31][ac];
      acc = __builtin_amdgcn_mfma_f32_32x32x16_bf16(Ah.s, Bh.s, acc, 0, 0, 0);
      acc = __builtin_amdgcn_mfma_f32_32x32x16_bf16(Al.s, Bh.s, acc, 0, 0, 0);
      acc = __builtin_amdgcn_mfma_f32_32x32x16_bf16(Ah.s, Bl.s, acc, 0, 0, 0);
    }
  }

  // epilogue: C/D layout col=l31, row=(r&3)+8*(r>>2)+4*lh
  int oc = colBase + wc * 32 + l31;
  int os3 = oc / 192, ooc = oc - os3 * 192;
  int hhc = ooc / 3, d = ooc - hhc * 3;
#pragma unroll
  for (int r = 0; r < 16; ++r) {
    int row = rowBase + wr * 32 + (r & 3) + 8 * (r >> 2) + 4 * lh;
    int b = row >> 10, s = row & (SS - 1);
    size_t bh = (size_t)(b * HH + hhc);
    float v = acc[r];
    if (os3 == 0) {
      Qf[(bh * SS + s) * 4 + d] = __float2bfloat16(v);
      if (d == 2) Qf[(bh * SS + s) * 4 + 3] = __float2bfloat16(0.0f);
    } else if (os3 == 1) {
      Kf[(bh * SS + s) * 4 + d] = __float2bfloat16(v);
      if (d == 2) Kf[(bh * SS + s) * 4 + 3] = __float2bfloat16(0.0f);
    } else {
      Vc[bh * (3 * SS) + (size_t)d * SS + s] = __float2bfloat16(v);
    }
  }
}

// MFMA attention (r14 proven body). Block = (head, query-eighth): 2048
// blocks. Swapped QK^T (A=K, B=Q) -> D[key][query]; B(=Q) zero for k>=3 so
// K is (S,4) bf16, A-frag {k-pair,0,0}. exp2 in-register, cvt_pk +
// permlane32_swap -> PV A-frags; V ones-column yields l via the PV MFMA.
// Structural floor ~41.4us across 7 variants (occupancy 26-45%, pins,
// unroll): trans-pipe ~27us busy + chain overhead. ONE S-tuple live at a
// time (dual-chain r10/r11 miscompiled).
__global__ __launch_bounds__(256, 4) void attn_k(
    const unsigned short* __restrict__ Qfg, const unsigned short* __restrict__ Kfg,
    const unsigned short* __restrict__ Vcg, float* __restrict__ AO)
{
  __shared__ __align__(16) short KfL[1024 * 4];   // 8 KB: [key][k0 k1 k2 0]
  __shared__ __align__(16) short VcL[4 * 1040];   // 8.1 KB: rows v0 v1 v2 ones
  int bh = blockIdx.x & 255;       // eighth-major: same-head blocks 256 apart (same XCD)
  int eighth = blockIdx.x >> 8;
  int b = bh >> 6, h = bh & 63;

  const uint2* ksrc = (const uint2*)Kfg + (size_t)bh * 1024;
  uint2* kdst = (uint2*)KfL;
  for (int i = threadIdx.x; i < 1024; i += 256) kdst[i] = ksrc[i];
  const uint4* vsrc = (const uint4*)Vcg + (size_t)bh * 384;
  for (int i = threadIdx.x; i < 384; i += 256) {
    int r = i >> 7, cq = i & 127;
    *(uint4*)(VcL + r * 1040 + cq * 8) = vsrc[i];
  }
  {
    unsigned v1 = 0x3F803F80u;
    for (int i = threadIdx.x; i < 128; i += 256)
      *(uint4*)(VcL + 3 * 1040 + i * 8) = make_uint4(v1, v1, v1, v1);
  }
  __syncthreads();

  int lane = threadIdx.x & 63, w = threadIdx.x >> 6;
  int h32 = lane >> 5;
  int col = lane & 31;
  int q32 = eighth * 128 + w * 32;

  // Q B-frag: direct bf16 pair load (h1 lanes = zero half of K-dim)
  uint2 qq = *(const uint2*)(Qfg + ((size_t)bh * SS + q32 + col) * 4);
  U4B bq; bq.u = make_uint4(h32 ? 0u : qq.x, h32 ? 0u : qq.y, 0u, 0u);

  const fx16 zc = {0,0,0,0, 0,0,0,0, 0,0,0,0, 0,0,0,0};
  fx16 accPV = zc;
  int vbase = (col & 3) * 1040 + 8 * h32;

  for (int kt = 0; kt < 32; ++kt) {
    uint2 kk = *(const uint2*)(KfL + (size_t)(kt * 32 + col) * 4);
    U4B ak; ak.u = make_uint4(kk.x, kk.y, 0u, 0u);
    U4B bv1; bv1.u = *(const uint4*)(VcL + vbase + kt * 32);
    U4B bv2; bv2.u = *(const uint4*)(VcL + vbase + kt * 32 + 16);

    fx16 S = __builtin_amdgcn_mfma_f32_32x32x16_bf16(ak.s, bq.s, zc, 0, 0, 0);
#pragma unroll
    for (int i = 0; i < 16; ++i) S[i] = fast_exp2(S[i]);
    unsigned u0, u1, u2, u3, u4, u5, u6, u7;
    asm("v_cvt_pk_bf16_f32 %0, %1, %2" : "=v"(u0) : "v"(S[0]),  "v"(S[1]));
    asm("v_cvt_pk_bf16_f32 %0, %1, %2" : "=v"(u1) : "v"(S[2]),  "v"(S[3]));
    asm("v_cvt_pk_bf16_f32 %0, %1, %2" : "=v"(u2) : "v"(S[4]),  "v"(S[5]));
    asm("v_cvt_pk_bf16_f32 %0, %1, %2" : "=v"(u3) : "v"(S[6]),  "v"(S[7]));
    asm("v_cvt_pk_bf16_f32 %0, %1, %2" : "=v"(u4) : "v"(S[8]),  "v"(S[9]));
    asm("v_cvt_pk_bf16_f32 %0, %1, %2" : "=v"(u5) : "v"(S[10]), "v"(S[11]));
    asm("v_cvt_pk_bf16_f32 %0, %1, %2" : "=v"(u6) : "v"(S[12]), "v"(S[13]));
    asm("v_cvt_pk_bf16_f32 %0, %1, %2" : "=v"(u7) : "v"(S[14]), "v"(S[15]));
    asm("v_permlane32_swap_b32 %0, %1" : "+v"(u0), "+v"(u2));
    asm("v_permlane32_swap_b32 %0, %1" : "+v"(u1), "+v"(u3));
    asm("v_permlane32_swap_b32 %0, %1" : "+v"(u4), "+v"(u6));
    asm("v_permlane32_swap_b32 %0, %1" : "+v"(u5), "+v"(u7));
    U4B p1; p1.u = make_uint4(u0, u1, u2, u3);
    U4B p2; p2.u = make_uint4(u4, u5, u6, u7);
    accPV = __builtin_amdgcn_mfma_f32_32x32x16_bf16(p1.s, bv1.s, accPV, 0, 0, 0);
    accPV = __builtin_amdgcn_mfma_f32_32x32x16_bf16(p2.s, bv2.s, accPV, 0, 0, 0);
  }

  // Epilogue: D_pv[query row][col]: col 0-2 = o, col 3 = l. Normalize + write.
  int base3 = (lane & 32) | 3;
  float inv[16];
#pragma unroll
  for (int rg = 0; rg < 16; ++rg)
    inv[rg] = __shfl(fast_rcp(accPV[rg]), base3, 64);
  if (col < 3) {
#pragma unroll
    for (int rg = 0; rg < 16; ++rg) {
      int row = (rg & 3) + 8 * (rg >> 2) + 4 * h32;
      AO[((size_t)(b * SS + q32 + row)) * EE + h * 3 + col] = accPV[rg] * inv[rg];
    }
  }
}

// Output projection, split-bf16 MFMA: out(4096x192) = AO @ Wo^T. grid (3,64).
// Wo hi/lo split inline during staging (replaces the fold_split pre-pass).
__global__ __launch_bounds__(256) void gemm_out_k(
    const float* __restrict__ AO, const float* __restrict__ Wo,
    float* __restrict__ out)
{
  __shared__ __align__(16) short xsh[64][72], xsl[64][72];
  __shared__ __align__(16) short wsh[64][72], wsl[64][72];
  int colBase = blockIdx.x * 64;
  int rowBase = blockIdx.y * 64;
  int t = threadIdx.x;
  int lane = t & 63, w = t >> 6;
  int wr = w >> 1, wc = w & 1;
  int l31 = lane & 31, lh = lane >> 5;

  const fx16 zc = {0,0,0,0, 0,0,0,0, 0,0,0,0, 0,0,0,0};
  fx16 acc = zc;

  int srow = t >> 2, sk = (t & 3) * 16;
  const float* wrow = Wo + (size_t)(colBase + srow) * EE;

  for (int kk = 0; kk < 3; ++kk) {
    int off = kk * 64 + sk;
    const float4* xg = (const float4*)&AO[(size_t)(rowBase + srow) * EE + off];
    float4 v0 = xg[0], v1 = xg[1], v2 = xg[2], v3 = xg[3];
    const float4* wg = (const float4*)(wrow + off);
    float4 w0 = wg[0], w1 = wg[1], w2 = wg[2], w3 = wg[3];

    unsigned hu[8], lu[8], whu[8], wlu[8];
    split2(v0.x, v0.y, hu[0], lu[0]); split2(v0.z, v0.w, hu[1], lu[1]);
    split2(v1.x, v1.y, hu[2], lu[2]); split2(v1.z, v1.w, hu[3], lu[3]);
    split2(v2.x, v2.y, hu[4], lu[4]); split2(v2.z, v2.w, hu[5], lu[5]);
    split2(v3.x, v3.y, hu[6], lu[6]); split2(v3.z, v3.w, hu[7], lu[7]);
    split2(w0.x, w0.y, whu[0], wlu[0]); split2(w0.z, w0.w, whu[1], wlu[1]);
    split2(w1.x, w1.y, whu[2], wlu[2]); split2(w1.z, w1.w, whu[3], wlu[3]);
    split2(w2.x, w2.y, whu[4], wlu[4]); split2(w2.z, w2.w, whu[5], wlu[5]);
    split2(w3.x, w3.y, whu[6], wlu[6]); split2(w3.z, w3.w, whu[7], wlu[7]);

    __syncthreads();
    *(uint4*)&xsh[srow][sk]     = make_uint4(hu[0], hu[1], hu[2], hu[3]);
    *(uint4*)&xsh[srow][sk + 8] = make_uint4(hu[4], hu[5], hu[6], hu[7]);
    *(uint4*)&xsl[srow][sk]     = make_uint4(lu[0], lu[1], lu[2], lu[3]);
    *(uint4*)&xsl[srow][sk + 8] = make_uint4(lu[4], lu[5], lu[6], lu[7]);
    *(uint4*)&wsh[srow][sk]     = make_uint4(whu[0], whu[1], whu[2], whu[3]);
    *(uint4*)&wsh[srow][sk + 8] = make_uint4(whu[4], whu[5], whu[6], whu[7]);
    *(uint4*)&wsl[srow][sk]     = make_uint4(wlu[0], wlu[1], wlu[2], wlu[3]);
    *(uint4*)&wsl[srow][sk + 8] = make_uint4(wlu[4], wlu[5], wlu[6], wlu[7]);
    __syncthreads();

#pragma unroll
    for (int ks = 0; ks < 4; ++ks) {
      int ac = ks * 16 + lh * 8;
      U4B Ah, Al, Bh, Bl;
      Ah.u = *(const uint4*)&xsh[wr * 32 + l31][ac];
      Al.u = *(const uint4*)&xsl[wr * 32 + l31][ac];
      Bh.u = *(const uint4*)&wsh[wc * 32 + l31][ac];
      Bl.u = *(const uint4*)&wsl[wc * 32 + l31][ac];
      acc = __builtin_amdgcn_mfma_f32_32x32x16_bf16(Ah.s, Bh.s, acc, 0, 0, 0);
      acc = __builtin_amdgcn_mfma_f32_32x32x16_bf16(Al.s, Bh.s, acc, 0, 0, 0);
      acc = __builtin_amdgcn_mfma_f32_32x32x16_bf16(Ah.s, Bl.s, acc, 0, 0, 0);
    }
  }

  int o = colBase + wc * 32 + l31;
#pragma unroll
  for (int r = 0; r < 16; ++r) {
    int row = rowBase + wr * 32 + (r & 3) + 8 * (r >> 2) + 4 * lh;
    out[(size_t)row * EE + o] = acc[r];
  }
}

extern "C" void kernel_launch(void* const* d_in, const int* in_sizes, int n_in,
                              void* d_out, int out_size, void* d_ws, size_t ws_size,
                              hipStream_t stream) {
  const float* x   = (const float*)d_in[0];
  const float* Wq  = (const float*)d_in[1];
  const float* Wk  = (const float*)d_in[2];
  const float* Wv  = (const float*)d_in[3];
  const float* Wo  = (const float*)d_in[4];
  const float* rot = (const float*)d_in[5];
  float* ws  = (float*)d_ws;
  unsigned short* Qf  = (unsigned short*)(ws + OFF_QF);
  unsigned short* Kf  = (unsigned short*)(ws + OFF_KF);
  unsigned short* Vc  = (unsigned short*)(ws + OFF_VC);
  float* AO  = ws + OFF_AO;
  float* out = (float*)d_out;

  gemm_qkv_k<<<dim3(9, 64), 256, 0, stream>>>(x, Wq, Wk, Wv, rot,
                                              (__hip_bfloat16*)Qf, (__hip_bfloat16*)Kf,
                                              (__hip_bfloat16*)Vc);
  attn_k<<<dim3(BH * 8), 256, 0, stream>>>(Qf, Kf, Vc, AO);
  gemm_out_k<<<dim3(3, 64), 256, 0, stream>>>(AO, Wo, out);
}